// Round 5
// baseline (686.177 us; speedup 1.0000x reference)
//
#include <hip/hip_runtime.h>
#include <math.h>

#define DEV __device__ __forceinline__

typedef __attribute__((ext_vector_type(8))) short short8;   // 8 bf16 (4 VGPRs)
typedef __attribute__((ext_vector_type(4))) float f32x4;    // MFMA acc
typedef float f32x4u __attribute__((ext_vector_type(4), aligned(4)));
typedef __attribute__((ext_vector_type(4))) unsigned int u32x4;
typedef __attribute__((ext_vector_type(4))) _Float16 h16x4;  // 8B of fp16

#define NEG_BIG (-3.0e38f)
#define CAPB 4096   // bucket capacity (mean 2176, +40 sigma)
#define CHUNK 4096  // edges staged per bucket_bin block

DEV float sigm(float x) { return 1.0f / (1.0f + __expf(-x)); }
DEV float leaky(float e) { return (e >= 0.0f) ? e : 0.2f * e; }

// split 8 fp32 -> bf16 hi (truncate) + bf16 lo (truncate of exact residual)
DEV void split_bf16(const float f[8], short8& hi, short8& lo) {
#pragma unroll
  for (int i = 0; i < 8; ++i) {
    unsigned u = __builtin_bit_cast(unsigned, f[i]);
    hi[i] = (short)(u >> 16);
    float h = __builtin_bit_cast(float, u & 0xffff0000u);
    float r = f[i] - h;  // exact (Dekker)
    lo[i] = (short)(__builtin_bit_cast(unsigned, r) >> 16);
  }
}

// fp32 -> packed u32 (bf16hi<<16 | bf16lo); numerics identical to split_bf16
DEV unsigned packsplit(float v) {
  unsigned u = __builtin_bit_cast(unsigned, v);
  unsigned hf = u & 0xffff0000u;
  float r = v - __builtin_bit_cast(float, hf);
  return hf | (__builtin_bit_cast(unsigned, r) >> 16);
}

// unpack 8 packed u32 -> hi/lo short8 via v_perm
DEV void unpack_pk(const u32x4 p0, const u32x4 p1, short8& hi, short8& lo) {
  u32x4 h, l;
  h[0] = __builtin_amdgcn_perm(p0[1], p0[0], 0x07060302u);
  h[1] = __builtin_amdgcn_perm(p0[3], p0[2], 0x07060302u);
  h[2] = __builtin_amdgcn_perm(p1[1], p1[0], 0x07060302u);
  h[3] = __builtin_amdgcn_perm(p1[3], p1[2], 0x07060302u);
  l[0] = __builtin_amdgcn_perm(p0[1], p0[0], 0x05040100u);
  l[1] = __builtin_amdgcn_perm(p0[3], p0[2], 0x05040100u);
  l[2] = __builtin_amdgcn_perm(p1[1], p1[0], 0x05040100u);
  l[3] = __builtin_amdgcn_perm(p1[3], p1[2], 0x05040100u);
  hi = __builtin_bit_cast(short8, h);
  lo = __builtin_bit_cast(short8, l);
}

// MFMA on one 4-tile n-group with compile-time group index G (static acc idx)
template <int G, int MT, int NT>
DEV void mfma_grp(f32x4 (&acc)[MT][NT], const short8 (&ah)[MT],
                  const short8 (&al)[MT], const short8 (&bh)[4],
                  const short8 (&bl)[4]) {
#pragma unroll
  for (int mt = 0; mt < MT; ++mt)
#pragma unroll
    for (int j = 0; j < 4; ++j) {
      acc[mt][G * 4 + j] = __builtin_amdgcn_mfma_f32_16x16x32_bf16(
          ah[mt], bh[j], acc[mt][G * 4 + j], 0, 0, 0);
      acc[mt][G * 4 + j] = __builtin_amdgcn_mfma_f32_16x16x32_bf16(
          ah[mt], bl[j], acc[mt][G * 4 + j], 0, 0, 0);
      acc[mt][G * 4 + j] = __builtin_amdgcn_mfma_f32_16x16x32_bf16(
          al[mt], bh[j], acc[mt][G * 4 + j], 0, 0, 0);
    }
}

// ============================ utility kernels ============================

__global__ void fill_i32_kernel(int* p, int v, int n) {
  int i = blockIdx.x * blockDim.x + threadIdx.x;
  if (i < n) p[i] = v;
}

// ============================ bucketed CSR build ============================

__global__ __launch_bounds__(256) void bucket_bin(
    const int* __restrict__ ei, int* __restrict__ bucket_cnt,
    unsigned* __restrict__ ebuf, int E, int Et) {
  __shared__ unsigned stage[CHUNK];  // 16 KB
  __shared__ int hist[512], rbase[512], lcur[512];
  const int tid = threadIdx.x;
  const long long e0 = (long long)blockIdx.x * CHUNK;
  const int nalive = (int)((Et - e0) < CHUNK ? (Et - e0) : CHUNK);
  for (int i = tid; i < 512; i += 256) hist[i] = 0;
  __syncthreads();
  for (int k = tid; k < nalive; k += 256) {
    long long e = e0 + k;
    int s, d;
    if (e < E) { s = ei[e]; d = ei[E + e]; } else { s = (int)(e - E); d = s; }
    unsigned p = (unsigned)s | ((unsigned)d << 16);  // src:16b | dst:16b
    stage[k] = p;
    atomicAdd(&hist[d >> 7], 1);
  }
  __syncthreads();
  for (int i = tid; i < 512; i += 256) {
    int c = hist[i];
    rbase[i] = c ? atomicAdd(&bucket_cnt[i], c) : 0;
    lcur[i] = 0;
  }
  __syncthreads();
  for (int k = tid; k < nalive; k += 256) {
    unsigned p = stage[k];
    int b = (int)(p >> 23);  // dst>>7
    int lofs = atomicAdd(&lcur[b], 1);
    int pos = rbase[b] + lofs;
    if (pos < CAPB) ebuf[(long long)b * CAPB + pos] = p;
  }
}

__global__ __launch_bounds__(512) void bucket_scan(
    const int* __restrict__ cnt, int* __restrict__ start, int Et) {
  __shared__ int sh[512];
  int tid = threadIdx.x;
  int v = cnt[tid];
  sh[tid] = v;
  __syncthreads();
  int val = v;
  for (int off = 1; off < 512; off <<= 1) {
    int add = (tid >= off) ? sh[tid - off] : 0;
    __syncthreads();
    val += add;
    sh[tid] = val;
    __syncthreads();
  }
  start[tid] = val - v;
  if (tid == 511) start[512] = Et;
}

__global__ __launch_bounds__(128) void bucket_csr(
    const unsigned* __restrict__ ebuf, const int* __restrict__ bucket_cnt,
    const int* __restrict__ bucket_start, int* __restrict__ row_start,
    int* __restrict__ srcs, int N, int Et) {
  __shared__ unsigned stage[CAPB];  // 16 KB
  __shared__ int hist[128], hbase[128], lcur[128];
  const int b = blockIdx.x, tid = threadIdx.x;
  int cnt = bucket_cnt[b];
  cnt = cnt < CAPB ? cnt : CAPB;
  const int gbase = bucket_start[b];
  hist[tid] = 0;
  __syncthreads();
  const unsigned* eb = ebuf + (long long)b * CAPB;
  for (int k = tid; k < cnt; k += 128) {
    unsigned p = eb[k];
    stage[k] = p;
    atomicAdd(&hist[(p >> 16) & 127], 1);
  }
  __syncthreads();
  int v = hist[tid];
  hbase[tid] = v;
  __syncthreads();
  int val = v;
  for (int off = 1; off < 128; off <<= 1) {
    int add = (tid >= off) ? hbase[tid - off] : 0;
    __syncthreads();
    val += add;
    hbase[tid] = val;
    __syncthreads();
  }
  int ex = val - v;
  row_start[b * 128 + tid] = gbase + ex;
  __syncthreads();
  hbase[tid] = ex;
  lcur[tid] = 0;
  __syncthreads();
  for (int k = tid; k < cnt; k += 128) {
    unsigned p = stage[k];
    int o = (p >> 16) & 127;
    int lofs = atomicAdd(&lcur[o], 1);
    srcs[gbase + hbase[o] + lofs] = (int)(p & 0xffffu);
  }
  if (b == 0 && tid == 0) row_start[N] = Et;
}

// ============================ fused W pre-split ============================
struct WJobs {
  const float* W[16];
  short* hi[16];
  short* lo[16];
  int K[16];
  int M16[16];
  int ldw[16];
  int skip[16];
  int tile0[16];
};

__global__ __launch_bounds__(64) void wsplit_all(WJobs jb, int njobs) {
  int b = blockIdx.x;
  int ji = 0;
#pragma unroll
  for (int i = 1; i < 16; ++i)
    if (i < njobs && b >= jb.tile0[i]) ji = i;
  int t = b - jb.tile0[ji];
  int M16 = jb.M16[ji];
  int kc = t / M16, ntG = t % M16;
  int K = jb.K[ji], ldw = jb.ldw[ji];
  const float* __restrict__ W = jb.W[ji];

  int lane = threadIdx.x;
  int kb = kc * 32 + (lane >> 4) * 8;
  int c = ntG * 16 + (lane & 15);
  if (jb.skip[ji] && c >= 64) c += 64;  // skip dead f-gate columns
  float f[8];
#pragma unroll
  for (int j = 0; j < 8; ++j) {
    int k = kb + j;
    f[j] = (k < K) ? W[(long long)k * ldw + c] : 0.0f;
  }
  short8 h, l;
  split_bf16(f, h, l);
  long long off = ((long long)t * 64 + lane) * 8;
  *(short8*)(jb.hi[ji] + off) = h;
  *(short8*)(jb.lo[ji] + off) = l;
}

// ============================ MFMA GEMM ============================
// Round 5: MT=1 -- one 16-row tile per wave, grid N/16 = 4096 blocks
// -> 4 waves/SIMD (was 2). TLP doubling is the latency-hiding lever the
// two ILP rounds (A-prefetch, B ping-pong, both kept) couldn't provide.
// B traffic doubles but is L2-resident (~15us aggregate, acceptable).
// OPK: 0 = fp32 C, 1 = packed bf16 hi/lo u32 C, 2 = fp16 C (GAT G matrix).
// STE=1: fused s/t epilogue (GAT).  STE=2: fused head (relu(acc+b)@w3 + b3
// reduced per row, direct store to out; C store skipped entirely).
template <int MT, int NT, int APK, int OPK, int STE>
__global__ __launch_bounds__(64) void gemm_mfma(
    const void* __restrict__ Av, int lda,
    const short* __restrict__ wh, const short* __restrict__ wl,
    const float* __restrict__ bias,
    void* __restrict__ Cv, int ldc,
    int K, int KC, int act,
    const float* __restrict__ asrc, const float* __restrict__ adst,
    float* __restrict__ sOut, float* __restrict__ tOut) {
  const int lane = threadIdx.x;
  const int m = lane & 15, q = lane >> 4;
  const long long r0 = (long long)blockIdx.x * (MT * 16);

  f32x4 acc[MT][NT];
#pragma unroll
  for (int i = 0; i < MT; ++i)
#pragma unroll
    for (int j = 0; j < NT; ++j) acc[i][j] = (f32x4)(0.0f);

  // raw A prefetch buffers (registers)
  u32x4 pA[MT][2];
  float fA[MT][8];

  auto loadA = [&](int kc) {
#pragma unroll
    for (int mt = 0; mt < MT; ++mt) {
      if (APK == 1) {
        const unsigned* ap =
            (const unsigned*)Av + (r0 + mt * 16 + m) * lda + kc * 32 + q * 8;
        pA[mt][0] = *(const u32x4*)ap;
        pA[mt][1] = *(const u32x4*)(ap + 4);
      } else {
        const float* ap =
            (const float*)Av + (r0 + mt * 16 + m) * lda + kc * 32 + q * 8;
        if (kc * 32 + 32 <= K) {
          f32x4u p0 = *(const f32x4u*)ap;
          f32x4u p1 = *(const f32x4u*)(ap + 4);
#pragma unroll
          for (int j = 0; j < 4; ++j) { fA[mt][j] = p0[j]; fA[mt][4 + j] = p1[j]; }
        } else {
#pragma unroll
          for (int j = 0; j < 8; ++j) {
            int k = kc * 32 + q * 8 + j;
            fA[mt][j] = (k < K) ? ap[j] : 0.0f;
          }
        }
      }
    }
  };

  short8 ah[MT], al[MT];
  auto unpackA = [&]() {
#pragma unroll
    for (int mt = 0; mt < MT; ++mt) {
      if (APK == 1)
        unpack_pk(pA[mt][0], pA[mt][1], ah[mt], al[mt]);
      else
        split_bf16(fA[mt], ah[mt], al[mt]);
    }
  };

  short8 bh0[4], bl0[4], bh1[4], bl1[4];
  auto loadB = [&](short8 (&bh)[4], short8 (&bl)[4], int kc, int g) {
#pragma unroll
    for (int j = 0; j < 4; ++j) {
      long long off = (((long long)kc * NT + (g * 4 + j)) * 64 + lane) * 8;
      bh[j] = *(const short8*)(wh + off);
      bl[j] = *(const short8*)(wl + off);
    }
  };

  if constexpr (NT == 4) {
    // one n-group: pipeline across kc, unrolled by 2 (KC here is 1 or even)
    loadA(0);
    loadB(bh0, bl0, 0, 0);
    int kc = 0;
    for (; kc + 2 <= KC; kc += 2) {
      unpackA();                       // A(kc)
      loadB(bh1, bl1, kc + 1, 0);      // prefetch B(kc+1)
      loadA(kc + 1);                   // prefetch A(kc+1) (after B: stays live)
      mfma_grp<0, MT, NT>(acc, ah, al, bh0, bl0);
      unpackA();                       // A(kc+1)
      if (kc + 2 < KC) {
        loadB(bh0, bl0, kc + 2, 0);
        loadA(kc + 2);
      }
      mfma_grp<0, MT, NT>(acc, ah, al, bh1, bl1);
    }
    if (kc < KC) {                     // tail: single unpipelined kc
      unpackA();
      mfma_grp<0, MT, NT>(acc, ah, al, bh0, bl0);
    }
  } else {  // NT == 8: two n-groups, natural ping-pong within each kc
    loadA(0);
    loadB(bh0, bl0, 0, 0);
    for (int kc = 0; kc < KC; ++kc) {
      unpackA();                       // A(kc)
      loadB(bh1, bl1, kc, 1);          // prefetch group 1
      if (kc + 1 < KC) loadA(kc + 1);  // prefetch next A
      mfma_grp<0, MT, NT>(acc, ah, al, bh0, bl0);
      if (kc + 1 < KC) loadB(bh0, bl0, kc + 1, 0);  // prefetch next kc g0
      mfma_grp<1, MT, NT>(acc, ah, al, bh1, bl1);
    }
  }

  if (STE == 2) {
    // fused head: out[r] = relu(acc[r,:] + bias) . w3 + b3  (no C store)
    float w3[NT], bs[NT];
#pragma unroll
    for (int nt = 0; nt < NT; ++nt) {
      int col = nt * 16 + m;
      w3[nt] = asrc[col];
      bs[nt] = bias[col];
    }
#pragma unroll
    for (int mt = 0; mt < MT; ++mt)
#pragma unroll
      for (int reg = 0; reg < 4; ++reg) {
        float ps = 0.0f;
#pragma unroll
        for (int nt = 0; nt < NT; ++nt) {
          float v = fmaxf(acc[mt][nt][reg] + bs[nt], 0.0f);
          ps = fmaf(v, w3[nt], ps);
        }
#pragma unroll
        for (int off = 1; off < 16; off <<= 1) ps += __shfl_xor(ps, off, 64);
        if (m == 0) sOut[r0 + mt * 16 + q * 4 + reg] = ps + adst[0];
      }
    return;
  }

#pragma unroll
  for (int nt = 0; nt < NT; ++nt) {
    int col = nt * 16 + m;
    float bsv = bias ? bias[col] : 0.0f;
#pragma unroll
    for (int mt = 0; mt < MT; ++mt) {
      long long rb = r0 + mt * 16 + q * 4;
#pragma unroll
      for (int reg = 0; reg < 4; ++reg) {
        float v = acc[mt][nt][reg] + bsv;
        if (act == 1) v = fmaxf(v, 0.0f);
        if (OPK == 1)
          ((unsigned*)Cv)[(rb + reg) * ldc + col] = packsplit(v);
        else if (OPK == 2)
          ((_Float16*)Cv)[(rb + reg) * ldc + col] = (_Float16)v;
        else
          ((float*)Cv)[(rb + reg) * ldc + col] = v;
      }
    }
  }

  if (STE == 1) {
    float as[NT], ad[NT];
#pragma unroll
    for (int nt = 0; nt < NT; ++nt) {
      int col = nt * 16 + m;
      as[nt] = asrc[col];
      ad[nt] = adst[col];
    }
#pragma unroll
    for (int mt = 0; mt < MT; ++mt)
#pragma unroll
      for (int reg = 0; reg < 4; ++reg) {
        float ps = 0.0f, pt = 0.0f;
#pragma unroll
        for (int nt = 0; nt < NT; ++nt) {
          ps = fmaf(acc[mt][nt][reg], as[nt], ps);
          pt = fmaf(acc[mt][nt][reg], ad[nt], pt);
        }
#pragma unroll
        for (int off = 1; off < 16; off <<= 1) {
          ps += __shfl_xor(ps, off, 64);
          pt += __shfl_xor(pt, off, 64);
        }
        if (m == 0) {
          long long r = r0 + mt * 16 + q * 4 + reg;
          sOut[r] = ps;
          tOut[r] = pt;
        }
      }
  }
}

// ============================ fused LSTM GEMM ============================
// One wave = 16 rows x all 192 packed gate cols (i,g,o): gi/gg/go for col
// c = nt*16+m live in acc[nt], acc[nt+4], acc[nt+8] -- same lane, same reg.
// B ping-pong: fragment for tile nt+2 is loading while tile nt computes;
// parity index is static after the #pragma unroll. Grid N/16 (4 waves/SIMD).
template <int APK>
__global__ __launch_bounds__(64) void gemm_lstm(
    const void* __restrict__ Av, int lda,
    const short* __restrict__ wh, const short* __restrict__ wl,
    const float* __restrict__ bias,   // original 256-wide lstm_b row
    unsigned* __restrict__ H,         // N x 64 packed h out
    int K, int KC) {
  const int lane = threadIdx.x;
  const int m = lane & 15, q = lane >> 4;
  const long long r0 = (long long)blockIdx.x * 16;

  f32x4 acc[12];
#pragma unroll
  for (int j = 0; j < 12; ++j) acc[j] = (f32x4)(0.0f);

  u32x4 pA[2];
  float fA[8];

  auto loadA = [&](int kc) {
    if (APK == 1) {
      const unsigned* ap = (const unsigned*)Av + (r0 + m) * lda + kc * 32 + q * 8;
      pA[0] = *(const u32x4*)ap;
      pA[1] = *(const u32x4*)(ap + 4);
    } else {
      const float* ap = (const float*)Av + (r0 + m) * lda + kc * 32 + q * 8;
      if (kc * 32 + 32 <= K) {
        f32x4u p0 = *(const f32x4u*)ap;
        f32x4u p1 = *(const f32x4u*)(ap + 4);
#pragma unroll
        for (int j = 0; j < 4; ++j) { fA[j] = p0[j]; fA[4 + j] = p1[j]; }
      } else {
#pragma unroll
        for (int j = 0; j < 8; ++j) {
          int k = kc * 32 + q * 8 + j;
          fA[j] = (k < K) ? ap[j] : 0.0f;
        }
      }
    }
  };

  short8 bh0, bl0, bh1, bl1;
  auto loadB = [&](short8& bh, short8& bl, int kc, int nt) {
    long long off = (((long long)kc * 12 + nt) * 64 + lane) * 8;
    bh = *(const short8*)(wh + off);
    bl = *(const short8*)(wl + off);
  };

  loadA(0);
  loadB(bh0, bl0, 0, 0);
  for (int kc = 0; kc < KC; ++kc) {
    short8 ah, al;
    if (APK == 1)
      unpack_pk(pA[0], pA[1], ah, al);
    else
      split_bf16(fA, ah, al);
    loadB(bh1, bl1, kc, 1);           // prefetch tile 1
    if (kc + 1 < KC) loadA(kc + 1);   // prefetch next A (after B: stays live)
    const int kn = (kc + 1 < KC) ? kc + 1 : kc;
#pragma unroll
    for (int nt = 0; nt < 12; ++nt) {
      short8& cbh = (nt & 1) ? bh1 : bh0;
      short8& cbl = (nt & 1) ? bl1 : bl0;
      acc[nt] = __builtin_amdgcn_mfma_f32_16x16x32_bf16(ah, cbh, acc[nt], 0, 0, 0);
      acc[nt] = __builtin_amdgcn_mfma_f32_16x16x32_bf16(ah, cbl, acc[nt], 0, 0, 0);
      acc[nt] = __builtin_amdgcn_mfma_f32_16x16x32_bf16(al, cbh, acc[nt], 0, 0, 0);
      if (nt + 2 < 12)
        loadB((nt & 1) ? bh1 : bh0, (nt & 1) ? bl1 : bl0, kc, nt + 2);
      else if (nt + 2 == 12)
        loadB(bh0, bl0, kn, 0);       // cross-kc prefetch of tile 0
    }
  }

#pragma unroll
  for (int nt = 0; nt < 4; ++nt) {
    int col = nt * 16 + m;
    float bi = bias[col], bg = bias[128 + col], bo = bias[192 + col];
#pragma unroll
    for (int reg = 0; reg < 4; ++reg) {
      float gi = acc[nt][reg] + bi;
      float gg = acc[nt + 4][reg] + bg;
      float go = acc[nt + 8][reg] + bo;
      float cc = sigm(gi) * tanhf(gg);
      H[(r0 + q * 4 + reg) * 64 + col] = packsplit(sigm(go) * tanhf(cc));
    }
  }
}

// ============================ GAT aggregate ============================
// G is fp16 (256B/row for FO=128): halves the random-gather byte volume
// (round-3 verified: bytes-bound at ~3.7 TB/s on the L2-miss path).
// Pass 1 caches alpha and src index in LDS; pass 2 is 4-edge unrolled.

template <int FO, int OPK>
__global__ __launch_bounds__(256) void gat_agg(
    const _Float16* __restrict__ G, const float* __restrict__ s,
    const float* __restrict__ t, const int* __restrict__ row_start,
    const int* __restrict__ srcs, const float* __restrict__ bias,
    void* __restrict__ outv, int ldc) {
  constexpr int CAP = 128;
  constexpr int LPE = FO / 4;
  constexpr int EPW = 64 / LPE;
  __shared__ float ecache[4][CAP];
  __shared__ int icache[4][CAP];
  const int wv = threadIdx.x >> 6;
  const int lane = threadIdx.x & 63;
  const int d = blockIdx.x * 4 + wv;
  const int start = row_start[d], end = row_start[d + 1];
  const float td = t[d];

  float m = NEG_BIG, dsum = 0.0f;
  for (int j = start + lane; j < end; j += 64) {
    int sj = srcs[j];
    float e = leaky(s[sj] + td);
    int idx = j - start;
    if (idx < CAP) { ecache[wv][idx] = e; icache[wv][idx] = sj; }
    float mn = fmaxf(m, e);
    dsum = dsum * __expf(m - mn) + __expf(e - mn);
    m = mn;
  }
#pragma unroll
  for (int off = 32; off; off >>= 1) {
    float mo = __shfl_xor(m, off, 64);
    float dso = __shfl_xor(dsum, off, 64);
    float mn = fmaxf(m, mo);
    dsum = dsum * __expf(m - mn) + dso * __expf(mo - mn);
    m = mn;
  }
  const float inv = 1.0f / dsum;

  const int deg = end - start;
  const int capdeg = deg < CAP ? deg : CAP;
  for (int idx = lane; idx < capdeg; idx += 64)
    ecache[wv][idx] = __expf(ecache[wv][idx] - m) * inv;
  __syncthreads();

  const int grp = lane / LPE, cl = lane % LPE;
  const _Float16* __restrict__ Gc = G + cl * 4;
  float a0 = 0.0f, a1 = 0.0f, a2 = 0.0f, a3 = 0.0f;
  int idx = grp;
  // 4-edge unrolled main loop over the LDS-cached region
  for (; idx + 3 * EPW < capdeg; idx += 4 * EPW) {
    const int i1 = idx + EPW, i2 = idx + 2 * EPW, i3 = idx + 3 * EPW;
    int s0 = icache[wv][idx], s1 = icache[wv][i1];
    int s2 = icache[wv][i2], s3 = icache[wv][i3];
    float l0 = ecache[wv][idx], l1 = ecache[wv][i1];
    float l2 = ecache[wv][i2], l3 = ecache[wv][i3];
    h16x4 g0 = *(const h16x4*)(Gc + (long long)s0 * FO);
    h16x4 g1 = *(const h16x4*)(Gc + (long long)s1 * FO);
    h16x4 g2 = *(const h16x4*)(Gc + (long long)s2 * FO);
    h16x4 g3 = *(const h16x4*)(Gc + (long long)s3 * FO);
    a0 = fmaf(l0, (float)g0[0], a0); a1 = fmaf(l0, (float)g0[1], a1);
    a2 = fmaf(l0, (float)g0[2], a2); a3 = fmaf(l0, (float)g0[3], a3);
    a0 = fmaf(l1, (float)g1[0], a0); a1 = fmaf(l1, (float)g1[1], a1);
    a2 = fmaf(l1, (float)g1[2], a2); a3 = fmaf(l1, (float)g1[3], a3);
    a0 = fmaf(l2, (float)g2[0], a0); a1 = fmaf(l2, (float)g2[1], a1);
    a2 = fmaf(l2, (float)g2[2], a2); a3 = fmaf(l2, (float)g2[3], a3);
    a0 = fmaf(l3, (float)g3[0], a0); a1 = fmaf(l3, (float)g3[1], a1);
    a2 = fmaf(l3, (float)g3[2], a2); a3 = fmaf(l3, (float)g3[3], a3);
  }
  // 2-edge tail
  for (; idx + EPW < capdeg; idx += 2 * EPW) {
    const int i1 = idx + EPW;
    int s0 = icache[wv][idx], s1 = icache[wv][i1];
    float l0 = ecache[wv][idx], l1 = ecache[wv][i1];
    h16x4 g0 = *(const h16x4*)(Gc + (long long)s0 * FO);
    h16x4 g1 = *(const h16x4*)(Gc + (long long)s1 * FO);
    a0 = fmaf(l0, (float)g0[0], a0); a1 = fmaf(l0, (float)g0[1], a1);
    a2 = fmaf(l0, (float)g0[2], a2); a3 = fmaf(l0, (float)g0[3], a3);
    a0 = fmaf(l1, (float)g1[0], a0); a1 = fmaf(l1, (float)g1[1], a1);
    a2 = fmaf(l1, (float)g1[2], a2); a3 = fmaf(l1, (float)g1[3], a3);
  }
  // 1-edge tail
  for (; idx < capdeg; idx += EPW) {
    int s0 = icache[wv][idx];
    float l0 = ecache[wv][idx];
    h16x4 g0 = *(const h16x4*)(Gc + (long long)s0 * FO);
    a0 = fmaf(l0, (float)g0[0], a0); a1 = fmaf(l0, (float)g0[1], a1);
    a2 = fmaf(l0, (float)g0[2], a2); a3 = fmaf(l0, (float)g0[3], a3);
  }
  // beyond-CAP fallback (deg > 128: essentially never at mean degree 17)
  for (; idx < deg; idx += EPW) {
    int s0 = srcs[start + idx];
    float l0 = __expf(leaky(s[s0] + td) - m) * inv;
    h16x4 g0 = *(const h16x4*)(Gc + (long long)s0 * FO);
    a0 = fmaf(l0, (float)g0[0], a0); a1 = fmaf(l0, (float)g0[1], a1);
    a2 = fmaf(l0, (float)g0[2], a2); a3 = fmaf(l0, (float)g0[3], a3);
  }
#pragma unroll
  for (int off = 32; off >= LPE; off >>= 1) {
    a0 += __shfl_xor(a0, off, 64);
    a1 += __shfl_xor(a1, off, 64);
    a2 += __shfl_xor(a2, off, 64);
    a3 += __shfl_xor(a3, off, 64);
  }
  if (grp == 0) {
    f32x4u bs = *(const f32x4u*)(bias + cl * 4);
    float v0 = fmaxf(a0 + bs[0], 0.0f);
    float v1 = fmaxf(a1 + bs[1], 0.0f);
    float v2 = fmaxf(a2 + bs[2], 0.0f);
    float v3 = fmaxf(a3 + bs[3], 0.0f);
    if (OPK == 1) {
      u32x4 pv;
      pv[0] = packsplit(v0); pv[1] = packsplit(v1);
      pv[2] = packsplit(v2); pv[3] = packsplit(v3);
      *(u32x4*)((unsigned*)outv + (long long)d * ldc + cl * 4) = pv;
    } else {
      f32x4u v; v[0] = v0; v[1] = v1; v[2] = v2; v[3] = v3;
      *(f32x4u*)((float*)outv + (long long)d * ldc + cl * 4) = v;
    }
  }
}

// ============================ launcher ============================

struct WSplit { const short* hi; const short* lo; };

extern "C" void kernel_launch(void* const* d_in, const int* in_sizes, int n_in,
                              void* d_out, int out_size, void* d_ws, size_t ws_size,
                              hipStream_t stream) {
  const int N = 65536, E = 1048576;
  const int Et = E + N;

  const float* x        = (const float*)d_in[0];
  const int*   ei       = (const int*)d_in[1];
  const float* poi1_W   = (const float*)d_in[2];
  const float* poi1_b   = (const float*)d_in[3];
  const float* poi2_W   = (const float*)d_in[4];
  const float* poi2_b   = (const float*)d_in[5];
  const float* svi1_W   = (const float*)d_in[6];
  const float* svi1_b   = (const float*)d_in[7];
  const float* svi2_W   = (const float*)d_in[8];
  const float* svi2_b   = (const float*)d_in[9];
  const float* all1_W   = (const float*)d_in[10];
  const float* all1_b   = (const float*)d_in[11];
  const float* all2_W   = (const float*)d_in[12];
  const float* all2_b   = (const float*)d_in[13];
  const float* gat1_W   = (const float*)d_in[14];
  const float* gat1_b   = (const float*)d_in[15];
  const float* gat1_as  = (const float*)d_in[16];
  const float* gat1_ad  = (const float*)d_in[17];
  const float* gat2_W   = (const float*)d_in[18];
  const float* gat2_b   = (const float*)d_in[19];
  const float* gat2_as  = (const float*)d_in[20];
  const float* gat2_ad  = (const float*)d_in[21];
  const float* gat3_W   = (const float*)d_in[22];
  const float* gat3_b   = (const float*)d_in[23];
  const float* gat3_as  = (const float*)d_in[24];
  const float* gat3_ad  = (const float*)d_in[25];
  const float* lstm_Wih0= (const float*)d_in[26];
  const float* lstm_Wih = (const float*)d_in[27];
  const float* lstm_b   = (const float*)d_in[29];
  const float* time1_W  = (const float*)d_in[30];
  const float* time1_b  = (const float*)d_in[31];
  const float* time2_W  = (const float*)d_in[32];
  const float* time2_b  = (const float*)d_in[33];
  const float* lin1_W   = (const float*)d_in[34];
  const float* lin1_b   = (const float*)d_in[35];
  const float* lin2_W   = (const float*)d_in[36];
  const float* lin2_b   = (const float*)d_in[37];
  const float* lin3_W   = (const float*)d_in[38];
  const float* lin3_b   = (const float*)d_in[39];
  float* out = (float*)d_out;

  // ---- workspace layout ----
  float* wsf   = (float*)d_ws;
  float* R192  = wsf;
  float* RA    = R192 + (size_t)N * 192;
  float* RA2   = RA + (size_t)N * 64;
  float* RB    = RA + (size_t)N * 128;
  float* Rz    = RB + (size_t)N * 256;
  float* sArr  = Rz + (size_t)N * 128;
  float* tArr  = sArr + N;
  int* ints         = (int*)(tArr + N);
  int* row_start    = ints;                        // N+1
  int* srcs         = row_start + (N + 1);         // Et
  int* bucket_cnt   = srcs + Et;                   // 512
  int* bucket_start = bucket_cnt + 512;            // 513
  unsigned* ebuf    = (unsigned*)(bucket_start + 513);  // 512*CAPB (8MB)
  short* pool = (short*)(((uintptr_t)(ebuf + 512 * CAPB) + 15) & ~(uintptr_t)15);

  WJobs jb{};
  int nj = 0, tiles = 0;
  auto split = [&](const float* W, int K, int M, int ldw, int skip) -> WSplit {
    int KC = (K + 31) / 32;
    size_t sz = (size_t)KC * M * 32;
    short* hi = pool; pool += sz;
    short* lo = pool; pool += sz;
    jb.W[nj] = W; jb.hi[nj] = hi; jb.lo[nj] = lo;
    jb.K[nj] = K; jb.M16[nj] = M / 16; jb.ldw[nj] = ldw; jb.skip[nj] = skip;
    jb.tile0[nj] = tiles;
    tiles += KC * (M / 16);
    ++nj;
    return {hi, lo};
  };

  // M=64 -> NT=4, M=128 -> NT=8; MT=1: grid N/16 = 4096 waves (4/SIMD)
  auto gemm = [&](const void* A, int lda, WSplit w, const float* bias,
                  void* C, int ldc, int K, int M, int act, int apk, int opk) {
    int KC = (K + 31) / 32;
    dim3 grid(N / 16), blk(64);
    if (M == 64) {
      if (apk == 0 && opk == 1)
        hipLaunchKernelGGL((gemm_mfma<1, 4, 0, 1, 0>), grid, blk, 0, stream,
                           A, lda, w.hi, w.lo, bias, C, ldc, K, KC, act,
                           nullptr, nullptr, nullptr, nullptr);
      else if (apk == 1 && opk == 1)
        hipLaunchKernelGGL((gemm_mfma<1, 4, 1, 1, 0>), grid, blk, 0, stream,
                           A, lda, w.hi, w.lo, bias, C, ldc, K, KC, act,
                           nullptr, nullptr, nullptr, nullptr);
      else if (apk == 1 && opk == 0)
        hipLaunchKernelGGL((gemm_mfma<1, 4, 1, 0, 0>), grid, blk, 0, stream,
                           A, lda, w.hi, w.lo, bias, C, ldc, K, KC, act,
                           nullptr, nullptr, nullptr, nullptr);
      else
        hipLaunchKernelGGL((gemm_mfma<1, 4, 0, 0, 0>), grid, blk, 0, stream,
                           A, lda, w.hi, w.lo, bias, C, ldc, K, KC, act,
                           nullptr, nullptr, nullptr, nullptr);
    } else {  // M == 128
      if (apk == 0 && opk == 1)
        hipLaunchKernelGGL((gemm_mfma<1, 8, 0, 1, 0>), grid, blk, 0, stream,
                           A, lda, w.hi, w.lo, bias, C, ldc, K, KC, act,
                           nullptr, nullptr, nullptr, nullptr);
      else if (apk == 1 && opk == 1)
        hipLaunchKernelGGL((gemm_mfma<1, 8, 1, 1, 0>), grid, blk, 0, stream,
                           A, lda, w.hi, w.lo, bias, C, ldc, K, KC, act,
                           nullptr, nullptr, nullptr, nullptr);
      else if (apk == 1 && opk == 0)
        hipLaunchKernelGGL((gemm_mfma<1, 8, 1, 0, 0>), grid, blk, 0, stream,
                           A, lda, w.hi, w.lo, bias, C, ldc, K, KC, act,
                           nullptr, nullptr, nullptr, nullptr);
      else
        hipLaunchKernelGGL((gemm_mfma<1, 8, 0, 0, 0>), grid, blk, 0, stream,
                           A, lda, w.hi, w.lo, bias, C, ldc, K, KC, act,
                           nullptr, nullptr, nullptr, nullptr);
    }
  };
  // GAT GEMM with fused s/t epilogue; C stored fp16 (OPK=2) for the gather
  auto gemm_st = [&](const void* A, WSplit w, void* G, int M,
                     const float* as_, const float* ad_) {
    dim3 grid(N / 16), blk(64);
    if (M == 128)
      hipLaunchKernelGGL((gemm_mfma<1, 8, 1, 2, 1>), grid, blk, 0, stream,
                         A, 128, w.hi, w.lo, (const float*)nullptr,
                         G, 128, 128, 4, 0, as_, ad_, sArr, tArr);
    else
      hipLaunchKernelGGL((gemm_mfma<1, 4, 1, 2, 1>), grid, blk, 0, stream,
                         A, 128, w.hi, w.lo, (const float*)nullptr,
                         G, 64, 128, 4, 0, as_, ad_, sArr, tArr);
  };

  // ---- register all weight splits, then ONE fused split launch ----
  WSplit wpoi1 = split(poi1_W, 13, 64, 64, 0);
  WSplit wpoi2 = split(poi2_W, 64, 64, 64, 0);
  WSplit wsvi1 = split(svi1_W, 365, 128, 128, 0);
  WSplit wsvi2 = split(svi2_W, 128, 128, 128, 0);
  WSplit wall1 = split(all1_W, 192, 128, 128, 0);
  WSplit wall2 = split(all2_W, 128, 128, 128, 0);
  WSplit wg1   = split(gat1_W, 128, 128, 128, 0);
  WSplit wg2   = split(gat2_W, 128, 128, 128, 0);
  WSplit wg3   = split(gat3_W, 128, 64, 64, 0);
  WSplit wls0  = split(lstm_Wih0, 24, 192, 256, 1);
  WSplit wls1  = split(lstm_Wih, 64, 192, 256, 1);
  WSplit wls2  = split(lstm_Wih + 64 * 256, 64, 192, 256, 1);
  WSplit wt1   = split(time1_W, 64, 64, 64, 0);
  WSplit wt2   = split(time2_W, 64, 64, 64, 0);
  WSplit wl1   = split(lin1_W, 128, 64, 64, 0);
  WSplit wl2   = split(lin2_W, 64, 64, 64, 0);
  hipLaunchKernelGGL(wsplit_all, dim3(tiles), dim3(64), 0, stream, jb, nj);

  const int TB = 256;

  // ---- build CSR via bucketed counting sort ----
  hipLaunchKernelGGL(fill_i32_kernel, dim3(2), dim3(TB), 0, stream,
                     bucket_cnt, 0, 512);
  hipLaunchKernelGGL(bucket_bin, dim3((Et + CHUNK - 1) / CHUNK), dim3(256),
                     0, stream, ei, bucket_cnt, ebuf, E, Et);
  hipLaunchKernelGGL(bucket_scan, dim3(1), dim3(512), 0, stream,
                     bucket_cnt, bucket_start, Et);
  hipLaunchKernelGGL(bucket_csr, dim3(512), dim3(128), 0, stream,
                     ebuf, bucket_cnt, bucket_start, row_start, srcs, N, Et);

  // ---- MLP towers (internal tensors packed) ----
  gemm(x + 3, 445, wpoi1, poi1_b, RA, 64, 13, 64, 1, 0, 1);
  gemm(RA, 64, wpoi2, poi2_b, R192, 192, 64, 64, 1, 1, 1);
  gemm(x + 56, 445, wsvi1, svi1_b, RB, 128, 365, 128, 1, 0, 1);
  gemm(RB, 128, wsvi2, svi2_b, R192 + 64, 192, 128, 128, 1, 1, 1);
  gemm(R192, 192, wall1, all1_b, RA, 128, 192, 128, 1, 1, 1);
  gemm(RA, 128, wall2, all2_b, RB, 128, 128, 128, 1, 1, 1);

  const int aggBlocks = N / 4;
  _Float16* Gh = (_Float16*)RA;  // fp16 G buffer (16MB for FO=128)

  // ---- GAT1: GEMM(+direct s/t epilogue, fp16 G) -> aggregate ----
  gemm_st(RB, wg1, Gh, 128, gat1_as, gat1_ad);
  hipLaunchKernelGGL((gat_agg<128, 1>), dim3(aggBlocks), dim3(256), 0, stream,
                     Gh, sArr, tArr, row_start, srcs, gat1_b, RB, 128);
  // ---- GAT2 ----
  gemm_st(RB, wg2, Gh, 128, gat2_as, gat2_ad);
  hipLaunchKernelGGL((gat_agg<128, 1>), dim3(aggBlocks), dim3(256), 0, stream,
                     Gh, sArr, tArr, row_start, srcs, gat2_b, RB, 128);
  // ---- GAT3 (fo=64 -> Rz cols 0..63 packed) ----
  gemm_st(RB, wg3, Gh, 64, gat3_as, gat3_ad);
  hipLaunchKernelGGL((gat_agg<64, 1>), dim3(aggBlocks), dim3(256), 0, stream,
                     Gh, sArr, tArr, row_start, srcs, gat3_b, Rz, 128);

  // ---- "LSTM": fused GEMM+activation, f-gate skipped, packed h ----
  hipLaunchKernelGGL((gemm_lstm<0>), dim3(N / 16), dim3(64), 0, stream,
                     x + 421, 445, wls0.hi, wls0.lo, lstm_b,
                     (unsigned*)RA, 24, 1);
  hipLaunchKernelGGL((gemm_lstm<1>), dim3(N / 16), dim3(64), 0, stream,
                     RA, 64, wls1.hi, wls1.lo, lstm_b + 256,
                     (unsigned*)RA2, 64, 2);
  hipLaunchKernelGGL((gemm_lstm<1>), dim3(N / 16), dim3(64), 0, stream,
                     RA2, 64, wls2.hi, wls2.lo, lstm_b + 512,
                     (unsigned*)RA, 64, 2);

  // ---- time MLP -> Rz cols 64..127 packed ----
  gemm(RA, 64, wt1, time1_b, RA2, 64, 64, 64, 1, 1, 1);
  gemm(RA2, 64, wt2, time2_b, Rz + 64, 128, 64, 64, 1, 1, 1);

  // ---- head: lin1 -> fused lin2+lin3 (STE=2, direct store to out) ----
  gemm(Rz, 128, wl1, lin1_b, RA, 64, 128, 64, 1, 1, 1);
  hipLaunchKernelGGL((gemm_mfma<1, 4, 1, 0, 2>), dim3(N / 16), dim3(64), 0, stream,
                     RA, 64, wl2.hi, wl2.lo, lin2_b, nullptr, 64, 64, 2, 0,
                     lin3_W, lin3_b, out, nullptr);
}

// Round 6
// 648.476 us; speedup vs baseline: 1.0581x; 1.0581x over previous
//
#include <hip/hip_runtime.h>
#include <math.h>

#define DEV __device__ __forceinline__

typedef __attribute__((ext_vector_type(8))) short short8;   // 8 bf16 (4 VGPRs)
typedef __attribute__((ext_vector_type(4))) float f32x4;    // MFMA acc
typedef float f32x4u __attribute__((ext_vector_type(4), aligned(4)));
typedef __attribute__((ext_vector_type(4))) unsigned int u32x4;
typedef __attribute__((ext_vector_type(4))) _Float16 h16x4;  // 8B of fp16

#define NEG_BIG (-3.0e38f)
#define CAPB 4096   // bucket capacity (mean 2176, +40 sigma)
#define CHUNK 4096  // edges staged per bucket_bin block

DEV float sigm(float x) { return 1.0f / (1.0f + __expf(-x)); }
DEV float leaky(float e) { return (e >= 0.0f) ? e : 0.2f * e; }

// split 8 fp32 -> bf16 hi (truncate) + bf16 lo (truncate of exact residual)
DEV void split_bf16(const float f[8], short8& hi, short8& lo) {
#pragma unroll
  for (int i = 0; i < 8; ++i) {
    unsigned u = __builtin_bit_cast(unsigned, f[i]);
    hi[i] = (short)(u >> 16);
    float h = __builtin_bit_cast(float, u & 0xffff0000u);
    float r = f[i] - h;  // exact (Dekker)
    lo[i] = (short)(__builtin_bit_cast(unsigned, r) >> 16);
  }
}

// fp32 -> packed u32 (bf16hi<<16 | bf16lo); numerics identical to split_bf16
DEV unsigned packsplit(float v) {
  unsigned u = __builtin_bit_cast(unsigned, v);
  unsigned hf = u & 0xffff0000u;
  float r = v - __builtin_bit_cast(float, hf);
  return hf | (__builtin_bit_cast(unsigned, r) >> 16);
}

// unpack 8 packed u32 -> hi/lo short8 via v_perm
DEV void unpack_pk(const u32x4 p0, const u32x4 p1, short8& hi, short8& lo) {
  u32x4 h, l;
  h[0] = __builtin_amdgcn_perm(p0[1], p0[0], 0x07060302u);
  h[1] = __builtin_amdgcn_perm(p0[3], p0[2], 0x07060302u);
  h[2] = __builtin_amdgcn_perm(p1[1], p1[0], 0x07060302u);
  h[3] = __builtin_amdgcn_perm(p1[3], p1[2], 0x07060302u);
  l[0] = __builtin_amdgcn_perm(p0[1], p0[0], 0x05040100u);
  l[1] = __builtin_amdgcn_perm(p0[3], p0[2], 0x05040100u);
  l[2] = __builtin_amdgcn_perm(p1[1], p1[0], 0x05040100u);
  l[3] = __builtin_amdgcn_perm(p1[3], p1[2], 0x05040100u);
  hi = __builtin_bit_cast(short8, h);
  lo = __builtin_bit_cast(short8, l);
}

// MFMA on one 4-tile n-group with compile-time group index G (static acc idx)
template <int G, int MT, int NT>
DEV void mfma_grp(f32x4 (&acc)[MT][NT], const short8 (&ah)[MT],
                  const short8 (&al)[MT], const short8 (&bh)[4],
                  const short8 (&bl)[4]) {
#pragma unroll
  for (int mt = 0; mt < MT; ++mt)
#pragma unroll
    for (int j = 0; j < 4; ++j) {
      acc[mt][G * 4 + j] = __builtin_amdgcn_mfma_f32_16x16x32_bf16(
          ah[mt], bh[j], acc[mt][G * 4 + j], 0, 0, 0);
      acc[mt][G * 4 + j] = __builtin_amdgcn_mfma_f32_16x16x32_bf16(
          ah[mt], bl[j], acc[mt][G * 4 + j], 0, 0, 0);
      acc[mt][G * 4 + j] = __builtin_amdgcn_mfma_f32_16x16x32_bf16(
          al[mt], bh[j], acc[mt][G * 4 + j], 0, 0, 0);
    }
}

// ============================ utility kernels ============================

__global__ void fill_i32_kernel(int* p, int v, int n) {
  int i = blockIdx.x * blockDim.x + threadIdx.x;
  if (i < n) p[i] = v;
}

// ============================ bucketed CSR build ============================

__global__ __launch_bounds__(256) void bucket_bin(
    const int* __restrict__ ei, int* __restrict__ bucket_cnt,
    unsigned* __restrict__ ebuf, int E, int Et) {
  __shared__ unsigned stage[CHUNK];  // 16 KB
  __shared__ int hist[512], rbase[512], lcur[512];
  const int tid = threadIdx.x;
  const long long e0 = (long long)blockIdx.x * CHUNK;
  const int nalive = (int)((Et - e0) < CHUNK ? (Et - e0) : CHUNK);
  for (int i = tid; i < 512; i += 256) hist[i] = 0;
  __syncthreads();
  for (int k = tid; k < nalive; k += 256) {
    long long e = e0 + k;
    int s, d;
    if (e < E) { s = ei[e]; d = ei[E + e]; } else { s = (int)(e - E); d = s; }
    unsigned p = (unsigned)s | ((unsigned)d << 16);  // src:16b | dst:16b
    stage[k] = p;
    atomicAdd(&hist[d >> 7], 1);
  }
  __syncthreads();
  for (int i = tid; i < 512; i += 256) {
    int c = hist[i];
    rbase[i] = c ? atomicAdd(&bucket_cnt[i], c) : 0;
    lcur[i] = 0;
  }
  __syncthreads();
  for (int k = tid; k < nalive; k += 256) {
    unsigned p = stage[k];
    int b = (int)(p >> 23);  // dst>>7
    int lofs = atomicAdd(&lcur[b], 1);
    int pos = rbase[b] + lofs;
    if (pos < CAPB) ebuf[(long long)b * CAPB + pos] = p;
  }
}

__global__ __launch_bounds__(512) void bucket_scan(
    const int* __restrict__ cnt, int* __restrict__ start, int Et) {
  __shared__ int sh[512];
  int tid = threadIdx.x;
  int v = cnt[tid];
  sh[tid] = v;
  __syncthreads();
  int val = v;
  for (int off = 1; off < 512; off <<= 1) {
    int add = (tid >= off) ? sh[tid - off] : 0;
    __syncthreads();
    val += add;
    sh[tid] = val;
    __syncthreads();
  }
  start[tid] = val - v;
  if (tid == 511) start[512] = Et;
}

__global__ __launch_bounds__(128) void bucket_csr(
    const unsigned* __restrict__ ebuf, const int* __restrict__ bucket_cnt,
    const int* __restrict__ bucket_start, int* __restrict__ row_start,
    int* __restrict__ srcs, int N, int Et) {
  __shared__ unsigned stage[CAPB];  // 16 KB
  __shared__ int hist[128], hbase[128], lcur[128];
  const int b = blockIdx.x, tid = threadIdx.x;
  int cnt = bucket_cnt[b];
  cnt = cnt < CAPB ? cnt : CAPB;
  const int gbase = bucket_start[b];
  hist[tid] = 0;
  __syncthreads();
  const unsigned* eb = ebuf + (long long)b * CAPB;
  for (int k = tid; k < cnt; k += 128) {
    unsigned p = eb[k];
    stage[k] = p;
    atomicAdd(&hist[(p >> 16) & 127], 1);
  }
  __syncthreads();
  int v = hist[tid];
  hbase[tid] = v;
  __syncthreads();
  int val = v;
  for (int off = 1; off < 128; off <<= 1) {
    int add = (tid >= off) ? hbase[tid - off] : 0;
    __syncthreads();
    val += add;
    hbase[tid] = val;
    __syncthreads();
  }
  int ex = val - v;
  row_start[b * 128 + tid] = gbase + ex;
  __syncthreads();
  hbase[tid] = ex;
  lcur[tid] = 0;
  __syncthreads();
  for (int k = tid; k < cnt; k += 128) {
    unsigned p = stage[k];
    int o = (p >> 16) & 127;
    int lofs = atomicAdd(&lcur[o], 1);
    srcs[gbase + hbase[o] + lofs] = (int)(p & 0xffffu);
  }
  if (b == 0 && tid == 0) row_start[N] = Et;
}

// ============================ fused W pre-split ============================
struct WJobs {
  const float* W[16];
  short* hi[16];
  short* lo[16];
  int K[16];
  int M16[16];
  int ldw[16];
  int skip[16];
  int tile0[16];
};

__global__ __launch_bounds__(64) void wsplit_all(WJobs jb, int njobs) {
  int b = blockIdx.x;
  int ji = 0;
#pragma unroll
  for (int i = 1; i < 16; ++i)
    if (i < njobs && b >= jb.tile0[i]) ji = i;
  int t = b - jb.tile0[ji];
  int M16 = jb.M16[ji];
  int kc = t / M16, ntG = t % M16;
  int K = jb.K[ji], ldw = jb.ldw[ji];
  const float* __restrict__ W = jb.W[ji];

  int lane = threadIdx.x;
  int kb = kc * 32 + (lane >> 4) * 8;
  int c = ntG * 16 + (lane & 15);
  if (jb.skip[ji] && c >= 64) c += 64;  // skip dead f-gate columns
  float f[8];
#pragma unroll
  for (int j = 0; j < 8; ++j) {
    int k = kb + j;
    f[j] = (k < K) ? W[(long long)k * ldw + c] : 0.0f;
  }
  short8 h, l;
  split_bf16(f, h, l);
  long long off = ((long long)t * 64 + lane) * 8;
  *(short8*)(jb.hi[ji] + off) = h;
  *(short8*)(jb.lo[ji] + off) = l;
}

// ============================ GEMM bodies (device) ============================
// Round 6: bodies factored into __device__ functions so INDEPENDENT GEMM jobs
// can be co-scheduled in ONE launch (blockIdx split, block-uniform branch).
// Round-5 counters showed every pipe idle (Mfma 8.5%, VALU 9%, HBM 12%) --
// serial dispatch of latency-bound kernels is the limiter, not intra-wave ILP.
// MT reverted to 2 (round-5's MT=1 doubled per-wave B traffic: regression).

struct GemmArgs {
  const void* A; const short* wh; const short* wl; const float* bias;
  void* C; const float* asrc; const float* adst; float* sOut; float* tOut;
  int lda, ldc, K, KC, act;
};

struct LstmArgs {
  const void* A; const short* wh; const short* wl; const float* bias;
  unsigned* H; int lda, K, KC;
};

template <int MT, int NT, int APK, int OPK, int STE>
DEV void gemm_body(const GemmArgs& g, int bid) {
  const int lane = threadIdx.x;
  const int m = lane & 15, q = lane >> 4;
  const long long r0 = (long long)bid * (MT * 16);
  const int K = g.K, KC = g.KC, lda = g.lda;

  f32x4 acc[MT][NT];
#pragma unroll
  for (int i = 0; i < MT; ++i)
#pragma unroll
    for (int j = 0; j < NT; ++j) acc[i][j] = (f32x4)(0.0f);

  u32x4 pA[MT][2];
  float fA[MT][8];

  auto loadA = [&](int kc) {
#pragma unroll
    for (int mt = 0; mt < MT; ++mt) {
      if (APK == 1) {
        const unsigned* ap =
            (const unsigned*)g.A + (r0 + mt * 16 + m) * lda + kc * 32 + q * 8;
        pA[mt][0] = *(const u32x4*)ap;
        pA[mt][1] = *(const u32x4*)(ap + 4);
      } else {
        const float* ap =
            (const float*)g.A + (r0 + mt * 16 + m) * lda + kc * 32 + q * 8;
        if (kc * 32 + 32 <= K) {
          f32x4u p0 = *(const f32x4u*)ap;
          f32x4u p1 = *(const f32x4u*)(ap + 4);
#pragma unroll
          for (int j = 0; j < 4; ++j) { fA[mt][j] = p0[j]; fA[mt][4 + j] = p1[j]; }
        } else {
#pragma unroll
          for (int j = 0; j < 8; ++j) {
            int k = kc * 32 + q * 8 + j;
            fA[mt][j] = (k < K) ? ap[j] : 0.0f;
          }
        }
      }
    }
  };

  short8 ah[MT], al[MT];
  auto unpackA = [&]() {
#pragma unroll
    for (int mt = 0; mt < MT; ++mt) {
      if (APK == 1)
        unpack_pk(pA[mt][0], pA[mt][1], ah[mt], al[mt]);
      else
        split_bf16(fA[mt], ah[mt], al[mt]);
    }
  };

  short8 bh0[4], bl0[4], bh1[4], bl1[4];
  auto loadB = [&](short8 (&bh)[4], short8 (&bl)[4], int kc, int gg) {
#pragma unroll
    for (int j = 0; j < 4; ++j) {
      long long off = (((long long)kc * NT + (gg * 4 + j)) * 64 + lane) * 8;
      bh[j] = *(const short8*)(g.wh + off);
      bl[j] = *(const short8*)(g.wl + off);
    }
  };

  if constexpr (NT == 4) {
    loadA(0);
    loadB(bh0, bl0, 0, 0);
    int kc = 0;
    for (; kc + 2 <= KC; kc += 2) {
      unpackA();
      loadB(bh1, bl1, kc + 1, 0);
      loadA(kc + 1);
      mfma_grp<0, MT, NT>(acc, ah, al, bh0, bl0);
      unpackA();
      if (kc + 2 < KC) {
        loadB(bh0, bl0, kc + 2, 0);
        loadA(kc + 2);
      }
      mfma_grp<0, MT, NT>(acc, ah, al, bh1, bl1);
    }
    if (kc < KC) {
      unpackA();
      mfma_grp<0, MT, NT>(acc, ah, al, bh0, bl0);
    }
  } else {  // NT == 8
    loadA(0);
    loadB(bh0, bl0, 0, 0);
    for (int kc = 0; kc < KC; ++kc) {
      unpackA();
      loadB(bh1, bl1, kc, 1);
      if (kc + 1 < KC) loadA(kc + 1);
      mfma_grp<0, MT, NT>(acc, ah, al, bh0, bl0);
      if (kc + 1 < KC) loadB(bh0, bl0, kc + 1, 0);
      mfma_grp<1, MT, NT>(acc, ah, al, bh1, bl1);
    }
  }

  if (STE == 2) {
    float w3[NT], bs[NT];
#pragma unroll
    for (int nt = 0; nt < NT; ++nt) {
      int col = nt * 16 + m;
      w3[nt] = g.asrc[col];
      bs[nt] = g.bias[col];
    }
#pragma unroll
    for (int mt = 0; mt < MT; ++mt)
#pragma unroll
      for (int reg = 0; reg < 4; ++reg) {
        float ps = 0.0f;
#pragma unroll
        for (int nt = 0; nt < NT; ++nt) {
          float v = fmaxf(acc[mt][nt][reg] + bs[nt], 0.0f);
          ps = fmaf(v, w3[nt], ps);
        }
#pragma unroll
        for (int off = 1; off < 16; off <<= 1) ps += __shfl_xor(ps, off, 64);
        if (m == 0) g.sOut[r0 + mt * 16 + q * 4 + reg] = ps + g.adst[0];
      }
    return;
  }

#pragma unroll
  for (int nt = 0; nt < NT; ++nt) {
    int col = nt * 16 + m;
    float bsv = g.bias ? g.bias[col] : 0.0f;
#pragma unroll
    for (int mt = 0; mt < MT; ++mt) {
      long long rb = r0 + mt * 16 + q * 4;
#pragma unroll
      for (int reg = 0; reg < 4; ++reg) {
        float v = acc[mt][nt][reg] + bsv;
        if (g.act == 1) v = fmaxf(v, 0.0f);
        if (OPK == 1)
          ((unsigned*)g.C)[(rb + reg) * g.ldc + col] = packsplit(v);
        else if (OPK == 2)
          ((_Float16*)g.C)[(rb + reg) * g.ldc + col] = (_Float16)v;
        else
          ((float*)g.C)[(rb + reg) * g.ldc + col] = v;
      }
    }
  }

  if (STE == 1) {
    float as[NT], ad[NT];
#pragma unroll
    for (int nt = 0; nt < NT; ++nt) {
      int col = nt * 16 + m;
      as[nt] = g.asrc[col];
      ad[nt] = g.adst[col];
    }
#pragma unroll
    for (int mt = 0; mt < MT; ++mt)
#pragma unroll
      for (int reg = 0; reg < 4; ++reg) {
        float ps = 0.0f, pt = 0.0f;
#pragma unroll
        for (int nt = 0; nt < NT; ++nt) {
          ps = fmaf(acc[mt][nt][reg], as[nt], ps);
          pt = fmaf(acc[mt][nt][reg], ad[nt], pt);
        }
#pragma unroll
        for (int off = 1; off < 16; off <<= 1) {
          ps += __shfl_xor(ps, off, 64);
          pt += __shfl_xor(pt, off, 64);
        }
        if (m == 0) {
          long long r = r0 + mt * 16 + q * 4 + reg;
          g.sOut[r] = ps;
          g.tOut[r] = pt;
        }
      }
  }
}

// fused LSTM GEMM body: 16 rows x 192 packed gate cols (i,g,o); B ping-pong.
template <int APK>
DEV void lstm_body(const LstmArgs& g, int bid) {
  const int lane = threadIdx.x;
  const int m = lane & 15, q = lane >> 4;
  const long long r0 = (long long)bid * 16;
  const int K = g.K, KC = g.KC, lda = g.lda;

  f32x4 acc[12];
#pragma unroll
  for (int j = 0; j < 12; ++j) acc[j] = (f32x4)(0.0f);

  u32x4 pA[2];
  float fA[8];

  auto loadA = [&](int kc) {
    if (APK == 1) {
      const unsigned* ap = (const unsigned*)g.A + (r0 + m) * lda + kc * 32 + q * 8;
      pA[0] = *(const u32x4*)ap;
      pA[1] = *(const u32x4*)(ap + 4);
    } else {
      const float* ap = (const float*)g.A + (r0 + m) * lda + kc * 32 + q * 8;
      if (kc * 32 + 32 <= K) {
        f32x4u p0 = *(const f32x4u*)ap;
        f32x4u p1 = *(const f32x4u*)(ap + 4);
#pragma unroll
        for (int j = 0; j < 4; ++j) { fA[j] = p0[j]; fA[4 + j] = p1[j]; }
      } else {
#pragma unroll
        for (int j = 0; j < 8; ++j) {
          int k = kc * 32 + q * 8 + j;
          fA[j] = (k < K) ? ap[j] : 0.0f;
        }
      }
    }
  };

  short8 bh0, bl0, bh1, bl1;
  auto loadB = [&](short8& bh, short8& bl, int kc, int nt) {
    long long off = (((long long)kc * 12 + nt) * 64 + lane) * 8;
    bh = *(const short8*)(g.wh + off);
    bl = *(const short8*)(g.wl + off);
  };

  loadA(0);
  loadB(bh0, bl0, 0, 0);
  for (int kc = 0; kc < KC; ++kc) {
    short8 ah, al;
    if (APK == 1)
      unpack_pk(pA[0], pA[1], ah, al);
    else
      split_bf16(fA, ah, al);
    loadB(bh1, bl1, kc, 1);
    if (kc + 1 < KC) loadA(kc + 1);
    const int kn = (kc + 1 < KC) ? kc + 1 : kc;
#pragma unroll
    for (int nt = 0; nt < 12; ++nt) {
      short8& cbh = (nt & 1) ? bh1 : bh0;
      short8& cbl = (nt & 1) ? bl1 : bl0;
      acc[nt] = __builtin_amdgcn_mfma_f32_16x16x32_bf16(ah, cbh, acc[nt], 0, 0, 0);
      acc[nt] = __builtin_amdgcn_mfma_f32_16x16x32_bf16(ah, cbl, acc[nt], 0, 0, 0);
      acc[nt] = __builtin_amdgcn_mfma_f32_16x16x32_bf16(al, cbh, acc[nt], 0, 0, 0);
      if (nt + 2 < 12)
        loadB((nt & 1) ? bh1 : bh0, (nt & 1) ? bl1 : bl0, kc, nt + 2);
      else if (nt + 2 == 12)
        loadB(bh0, bl0, kn, 0);
    }
  }

#pragma unroll
  for (int nt = 0; nt < 4; ++nt) {
    int col = nt * 16 + m;
    float bi = g.bias[col], bg = g.bias[128 + col], bo = g.bias[192 + col];
#pragma unroll
    for (int reg = 0; reg < 4; ++reg) {
      float gi = acc[nt][reg] + bi;
      float gg = acc[nt + 4][reg] + bg;
      float go = acc[nt + 8][reg] + bo;
      float cc = sigm(gi) * tanhf(gg);
      g.H[(r0 + q * 4 + reg) * 64 + col] = packsplit(sigm(go) * tanhf(cc));
    }
  }
}

// ============================ kernels ============================

template <int MT, int NT, int APK, int OPK, int STE>
__global__ __launch_bounds__(64) void gemm_mfma(GemmArgs g) {
  gemm_body<MT, NT, APK, OPK, STE>(g, blockIdx.x);
}

// two independent GEMM jobs in one launch
template <int NTa, int APKa, int OPKa, int STEa,
          int NTb, int APKb, int OPKb, int STEb>
__global__ __launch_bounds__(64) void combo_gg(GemmArgs a, GemmArgs b, int nA) {
  int bid = blockIdx.x;
  if (bid < nA)
    gemm_body<2, NTa, APKa, OPKa, STEa>(a, bid);
  else
    gemm_body<2, NTb, APKb, OPKb, STEb>(b, bid - nA);
}

// one GEMM + one LSTM job
template <int NTa, int APKa, int OPKa, int STEa, int LAPK>
__global__ __launch_bounds__(64) void combo_gl(GemmArgs a, LstmArgs l, int nA) {
  int bid = blockIdx.x;
  if (bid < nA)
    gemm_body<2, NTa, APKa, OPKa, STEa>(a, bid);
  else
    lstm_body<LAPK>(l, bid - nA);
}

// two GEMMs + one LSTM job
template <int NTa, int APKa, int OPKa, int STEa,
          int NTb, int APKb, int OPKb, int STEb, int LAPK>
__global__ __launch_bounds__(64) void combo_ggl(GemmArgs a, GemmArgs b,
                                                LstmArgs l, int nA, int nAB) {
  int bid = blockIdx.x;
  if (bid < nA)
    gemm_body<2, NTa, APKa, OPKa, STEa>(a, bid);
  else if (bid < nAB)
    gemm_body<2, NTb, APKb, OPKb, STEb>(b, bid - nA);
  else
    lstm_body<LAPK>(l, bid - nAB);
}

// ============================ GAT aggregate ============================
// G is fp16 (256B/row for FO=128): halves the random-gather byte volume
// (round-3 verified: bytes-bound at ~3.7 TB/s on the L2-miss path).

template <int FO, int OPK>
__global__ __launch_bounds__(256) void gat_agg(
    const _Float16* __restrict__ G, const float* __restrict__ s,
    const float* __restrict__ t, const int* __restrict__ row_start,
    const int* __restrict__ srcs, const float* __restrict__ bias,
    void* __restrict__ outv, int ldc) {
  constexpr int CAP = 128;
  constexpr int LPE = FO / 4;
  constexpr int EPW = 64 / LPE;
  __shared__ float ecache[4][CAP];
  __shared__ int icache[4][CAP];
  const int wv = threadIdx.x >> 6;
  const int lane = threadIdx.x & 63;
  const int d = blockIdx.x * 4 + wv;
  const int start = row_start[d], end = row_start[d + 1];
  const float td = t[d];

  float m = NEG_BIG, dsum = 0.0f;
  for (int j = start + lane; j < end; j += 64) {
    int sj = srcs[j];
    float e = leaky(s[sj] + td);
    int idx = j - start;
    if (idx < CAP) { ecache[wv][idx] = e; icache[wv][idx] = sj; }
    float mn = fmaxf(m, e);
    dsum = dsum * __expf(m - mn) + __expf(e - mn);
    m = mn;
  }
#pragma unroll
  for (int off = 32; off; off >>= 1) {
    float mo = __shfl_xor(m, off, 64);
    float dso = __shfl_xor(dsum, off, 64);
    float mn = fmaxf(m, mo);
    dsum = dsum * __expf(m - mn) + dso * __expf(mo - mn);
    m = mn;
  }
  const float inv = 1.0f / dsum;

  const int deg = end - start;
  const int capdeg = deg < CAP ? deg : CAP;
  for (int idx = lane; idx < capdeg; idx += 64)
    ecache[wv][idx] = __expf(ecache[wv][idx] - m) * inv;
  __syncthreads();

  const int grp = lane / LPE, cl = lane % LPE;
  const _Float16* __restrict__ Gc = G + cl * 4;
  float a0 = 0.0f, a1 = 0.0f, a2 = 0.0f, a3 = 0.0f;
  int idx = grp;
  for (; idx + 3 * EPW < capdeg; idx += 4 * EPW) {
    const int i1 = idx + EPW, i2 = idx + 2 * EPW, i3 = idx + 3 * EPW;
    int s0 = icache[wv][idx], s1 = icache[wv][i1];
    int s2 = icache[wv][i2], s3 = icache[wv][i3];
    float l0 = ecache[wv][idx], l1 = ecache[wv][i1];
    float l2 = ecache[wv][i2], l3 = ecache[wv][i3];
    h16x4 g0 = *(const h16x4*)(Gc + (long long)s0 * FO);
    h16x4 g1 = *(const h16x4*)(Gc + (long long)s1 * FO);
    h16x4 g2 = *(const h16x4*)(Gc + (long long)s2 * FO);
    h16x4 g3 = *(const h16x4*)(Gc + (long long)s3 * FO);
    a0 = fmaf(l0, (float)g0[0], a0); a1 = fmaf(l0, (float)g0[1], a1);
    a2 = fmaf(l0, (float)g0[2], a2); a3 = fmaf(l0, (float)g0[3], a3);
    a0 = fmaf(l1, (float)g1[0], a0); a1 = fmaf(l1, (float)g1[1], a1);
    a2 = fmaf(l1, (float)g1[2], a2); a3 = fmaf(l1, (float)g1[3], a3);
    a0 = fmaf(l2, (float)g2[0], a0); a1 = fmaf(l2, (float)g2[1], a1);
    a2 = fmaf(l2, (float)g2[2], a2); a3 = fmaf(l2, (float)g2[3], a3);
    a0 = fmaf(l3, (float)g3[0], a0); a1 = fmaf(l3, (float)g3[1], a1);
    a2 = fmaf(l3, (float)g3[2], a2); a3 = fmaf(l3, (float)g3[3], a3);
  }
  for (; idx + EPW < capdeg; idx += 2 * EPW) {
    const int i1 = idx + EPW;
    int s0 = icache[wv][idx], s1 = icache[wv][i1];
    float l0 = ecache[wv][idx], l1 = ecache[wv][i1];
    h16x4 g0 = *(const h16x4*)(Gc + (long long)s0 * FO);
    h16x4 g1 = *(const h16x4*)(Gc + (long long)s1 * FO);
    a0 = fmaf(l0, (float)g0[0], a0); a1 = fmaf(l0, (float)g0[1], a1);
    a2 = fmaf(l0, (float)g0[2], a2); a3 = fmaf(l0, (float)g0[3], a3);
    a0 = fmaf(l1, (float)g1[0], a0); a1 = fmaf(l1, (float)g1[1], a1);
    a2 = fmaf(l1, (float)g1[2], a2); a3 = fmaf(l1, (float)g1[3], a3);
  }
  for (; idx < capdeg; idx += EPW) {
    int s0 = icache[wv][idx];
    float l0 = ecache[wv][idx];
    h16x4 g0 = *(const h16x4*)(Gc + (long long)s0 * FO);
    a0 = fmaf(l0, (float)g0[0], a0); a1 = fmaf(l0, (float)g0[1], a1);
    a2 = fmaf(l0, (float)g0[2], a2); a3 = fmaf(l0, (float)g0[3], a3);
  }
  for (; idx < deg; idx += EPW) {
    int s0 = srcs[start + idx];
    float l0 = __expf(leaky(s[s0] + td) - m) * inv;
    h16x4 g0 = *(const h16x4*)(Gc + (long long)s0 * FO);
    a0 = fmaf(l0, (float)g0[0], a0); a1 = fmaf(l0, (float)g0[1], a1);
    a2 = fmaf(l0, (float)g0[2], a2); a3 = fmaf(l0, (float)g0[3], a3);
  }
#pragma unroll
  for (int off = 32; off >= LPE; off >>= 1) {
    a0 += __shfl_xor(a0, off, 64);
    a1 += __shfl_xor(a1, off, 64);
    a2 += __shfl_xor(a2, off, 64);
    a3 += __shfl_xor(a3, off, 64);
  }
  if (grp == 0) {
    f32x4u bs = *(const f32x4u*)(bias + cl * 4);
    float v0 = fmaxf(a0 + bs[0], 0.0f);
    float v1 = fmaxf(a1 + bs[1], 0.0f);
    float v2 = fmaxf(a2 + bs[2], 0.0f);
    float v3 = fmaxf(a3 + bs[3], 0.0f);
    if (OPK == 1) {
      u32x4 pv;
      pv[0] = packsplit(v0); pv[1] = packsplit(v1);
      pv[2] = packsplit(v2); pv[3] = packsplit(v3);
      *(u32x4*)((unsigned*)outv + (long long)d * ldc + cl * 4) = pv;
    } else {
      f32x4u v; v[0] = v0; v[1] = v1; v[2] = v2; v[3] = v3;
      *(f32x4u*)((float*)outv + (long long)d * ldc + cl * 4) = v;
    }
  }
}

// ============================ launcher ============================

struct WSplit { const short* hi; const short* lo; };

extern "C" void kernel_launch(void* const* d_in, const int* in_sizes, int n_in,
                              void* d_out, int out_size, void* d_ws, size_t ws_size,
                              hipStream_t stream) {
  const int N = 65536, E = 1048576;
  const int Et = E + N;

  const float* x        = (const float*)d_in[0];
  const int*   ei       = (const int*)d_in[1];
  const float* poi1_W   = (const float*)d_in[2];
  const float* poi1_b   = (const float*)d_in[3];
  const float* poi2_W   = (const float*)d_in[4];
  const float* poi2_b   = (const float*)d_in[5];
  const float* svi1_W   = (const float*)d_in[6];
  const float* svi1_b   = (const float*)d_in[7];
  const float* svi2_W   = (const float*)d_in[8];
  const float* svi2_b   = (const float*)d_in[9];
  const float* all1_W   = (const float*)d_in[10];
  const float* all1_b   = (const float*)d_in[11];
  const float* all2_W   = (const float*)d_in[12];
  const float* all2_b   = (const float*)d_in[13];
  const float* gat1_W   = (const float*)d_in[14];
  const float* gat1_b   = (const float*)d_in[15];
  const float* gat1_as  = (const float*)d_in[16];
  const float* gat1_ad  = (const float*)d_in[17];
  const float* gat2_W   = (const float*)d_in[18];
  const float* gat2_b   = (const float*)d_in[19];
  const float* gat2_as  = (const float*)d_in[20];
  const float* gat2_ad  = (const float*)d_in[21];
  const float* gat3_W   = (const float*)d_in[22];
  const float* gat3_b   = (const float*)d_in[23];
  const float* gat3_as  = (const float*)d_in[24];
  const float* gat3_ad  = (const float*)d_in[25];
  const float* lstm_Wih0= (const float*)d_in[26];
  const float* lstm_Wih = (const float*)d_in[27];
  const float* lstm_b   = (const float*)d_in[29];
  const float* time1_W  = (const float*)d_in[30];
  const float* time1_b  = (const float*)d_in[31];
  const float* time2_W  = (const float*)d_in[32];
  const float* time2_b  = (const float*)d_in[33];
  const float* lin1_W   = (const float*)d_in[34];
  const float* lin1_b   = (const float*)d_in[35];
  const float* lin2_W   = (const float*)d_in[36];
  const float* lin2_b   = (const float*)d_in[37];
  const float* lin3_W   = (const float*)d_in[38];
  const float* lin3_b   = (const float*)d_in[39];
  float* out = (float*)d_out;

  // ---- workspace layout ----
  float* wsf   = (float*)d_ws;
  float* R192  = wsf;
  float* RA    = R192 + (size_t)N * 192;   // N x 128 region (also fp16 G)
  float* RB    = RA + (size_t)N * 128;     // N x 128 packed
  float* Rz    = RB + (size_t)N * 128;     // N x 128 packed (GAT3 | time)
  float* LA    = Rz + (size_t)N * 128;     // lstm/time ping (N x 64)
  float* LB    = LA + (size_t)N * 64;      // lstm/time pong (N x 64)
  float* sArr  = LB + (size_t)N * 64;
  float* tArr  = sArr + N;
  int* ints         = (int*)(tArr + N);
  int* row_start    = ints;                        // N+1
  int* srcs         = row_start + (N + 1);         // Et
  int* bucket_cnt   = srcs + Et;                   // 512
  int* bucket_start = bucket_cnt + 512;            // 513
  unsigned* ebuf    = (unsigned*)(bucket_start + 513);  // 512*CAPB (8MB)
  short* pool = (short*)(((uintptr_t)(ebuf + 512 * CAPB) + 15) & ~(uintptr_t)15);

  WJobs jb{};
  int nj = 0, tiles = 0;
  auto split = [&](const float* W, int K, int M, int ldw, int skip) -> WSplit {
    int KC = (K + 31) / 32;
    size_t sz = (size_t)KC * M * 32;
    short* hi = pool; pool += sz;
    short* lo = pool; pool += sz;
    jb.W[nj] = W; jb.hi[nj] = hi; jb.lo[nj] = lo;
    jb.K[nj] = K; jb.M16[nj] = M / 16; jb.ldw[nj] = ldw; jb.skip[nj] = skip;
    jb.tile0[nj] = tiles;
    tiles += KC * (M / 16);
    ++nj;
    return {hi, lo};
  };

  auto mkg = [&](const void* A, int lda, WSplit w, const float* bias, void* C,
                 int ldc, int K, int act, const float* as_ = nullptr,
                 const float* ad_ = nullptr, float* sO = nullptr,
                 float* tO = nullptr) -> GemmArgs {
    GemmArgs g;
    g.A = A; g.lda = lda; g.wh = w.hi; g.wl = w.lo; g.bias = bias;
    g.C = C; g.ldc = ldc; g.K = K; g.KC = (K + 31) / 32; g.act = act;
    g.asrc = as_; g.adst = ad_; g.sOut = sO; g.tOut = tO;
    return g;
  };
  auto mkl = [&](const void* A, int lda, WSplit w, const float* bias,
                 unsigned* H, int K) -> LstmArgs {
    LstmArgs l;
    l.A = A; l.lda = lda; l.wh = w.hi; l.wl = w.lo; l.bias = bias;
    l.H = H; l.K = K; l.KC = (K + 31) / 32;
    return l;
  };

  // ---- register all weight splits, then ONE fused split launch ----
  WSplit wpoi1 = split(poi1_W, 13, 64, 64, 0);
  WSplit wpoi2 = split(poi2_W, 64, 64, 64, 0);
  WSplit wsvi1 = split(svi1_W, 365, 128, 128, 0);
  WSplit wsvi2 = split(svi2_W, 128, 128, 128, 0);
  WSplit wall1 = split(all1_W, 192, 128, 128, 0);
  WSplit wall2 = split(all2_W, 128, 128, 128, 0);
  WSplit wg1   = split(gat1_W, 128, 128, 128, 0);
  WSplit wg2   = split(gat2_W, 128, 128, 128, 0);
  WSplit wg3   = split(gat3_W, 128, 64, 64, 0);
  WSplit wls0  = split(lstm_Wih0, 24, 192, 256, 1);
  WSplit wls1  = split(lstm_Wih, 64, 192, 256, 1);
  WSplit wls2  = split(lstm_Wih + 64 * 256, 64, 192, 256, 1);
  WSplit wt1   = split(time1_W, 64, 64, 64, 0);
  WSplit wt2   = split(time2_W, 64, 64, 64, 0);
  WSplit wl1   = split(lin1_W, 128, 64, 64, 0);
  WSplit wl2   = split(lin2_W, 64, 64, 64, 0);
  hipLaunchKernelGGL(wsplit_all, dim3(tiles), dim3(64), 0, stream, jb, nj);

  const int TB = 256;
  const int GB = N / 32;   // gemm blocks (MT=2)
  const int LBK = N / 16;  // lstm blocks

  // ---- build CSR via bucketed counting sort ----
  hipLaunchKernelGGL(fill_i32_kernel, dim3(2), dim3(TB), 0, stream,
                     bucket_cnt, 0, 512);
  hipLaunchKernelGGL(bucket_bin, dim3((Et + CHUNK - 1) / CHUNK), dim3(256),
                     0, stream, ei, bucket_cnt, ebuf, E, Et);
  hipLaunchKernelGGL(bucket_scan, dim3(1), dim3(512), 0, stream,
                     bucket_cnt, bucket_start, Et);
  hipLaunchKernelGGL(bucket_csr, dim3(512), dim3(128), 0, stream,
                     ebuf, bucket_cnt, bucket_start, row_start, srcs, N, Et);

  _Float16* Gh = (_Float16*)RA;  // fp16 G buffer aliases RA region

  // ---- C1: svi1 | poi1 | ls0 (all read x; disjoint outputs) ----
  hipLaunchKernelGGL((combo_ggl<8, 0, 1, 0, 4, 0, 1, 0, 0>),
                     dim3(GB + GB + LBK), dim3(64), 0, stream,
                     mkg(x + 56, 445, wsvi1, svi1_b, RB, 128, 365, 1),
                     mkg(x + 3, 445, wpoi1, poi1_b, RA, 64, 13, 1),
                     mkl(x + 421, 445, wls0, lstm_b, (unsigned*)LA, 24),
                     GB, GB + GB);
  // ---- C2: svi2 | poi2 | ls1 ----
  hipLaunchKernelGGL((combo_ggl<8, 1, 1, 0, 4, 1, 1, 0, 1>),
                     dim3(GB + GB + LBK), dim3(64), 0, stream,
                     mkg(RB, 128, wsvi2, svi2_b, R192 + 64, 192, 128, 1),
                     mkg(RA, 64, wpoi2, poi2_b, R192, 192, 64, 1),
                     mkl(LA, 64, wls1, lstm_b + 256, (unsigned*)LB, 64),
                     GB, GB + GB);
  // ---- C3: all1 | ls2 ----
  hipLaunchKernelGGL((combo_gl<8, 1, 1, 0, 1>),
                     dim3(GB + LBK), dim3(64), 0, stream,
                     mkg(R192, 192, wall1, all1_b, RA, 128, 192, 1),
                     mkl(LB, 64, wls2, lstm_b + 512, (unsigned*)LA, 64), GB);
  // ---- C4: all2 | time1 ----
  hipLaunchKernelGGL((combo_gg<8, 1, 1, 0, 4, 1, 1, 0>),
                     dim3(GB + GB), dim3(64), 0, stream,
                     mkg(RA, 128, wall2, all2_b, RB, 128, 128, 1),
                     mkg(LA, 64, wt1, time1_b, LB, 64, 64, 1), GB);
  // ---- C5: gat1 GEMM(+s/t epi, fp16 G) | time2 (-> Rz cols 64..127) ----
  hipLaunchKernelGGL((combo_gg<8, 1, 2, 1, 4, 1, 1, 0>),
                     dim3(GB + GB), dim3(64), 0, stream,
                     mkg(RB, 128, wg1, nullptr, Gh, 128, 128, 0,
                         gat1_as, gat1_ad, sArr, tArr),
                     mkg(LB, 64, wt2, time2_b, Rz + 64, 128, 64, 1), GB);

  const int aggBlocks = N / 4;

  hipLaunchKernelGGL((gat_agg<128, 1>), dim3(aggBlocks), dim3(256), 0, stream,
                     Gh, sArr, tArr, row_start, srcs, gat1_b, RB, 128);
  // ---- GAT2 ----
  hipLaunchKernelGGL((gemm_mfma<2, 8, 1, 2, 1>), dim3(GB), dim3(64), 0, stream,
                     mkg(RB, 128, wg2, nullptr, Gh, 128, 128, 0,
                         gat2_as, gat2_ad, sArr, tArr));
  hipLaunchKernelGGL((gat_agg<128, 1>), dim3(aggBlocks), dim3(256), 0, stream,
                     Gh, sArr, tArr, row_start, srcs, gat2_b, RB, 128);
  // ---- GAT3 (fo=64) ----
  hipLaunchKernelGGL((gemm_mfma<2, 4, 1, 2, 1>), dim3(GB), dim3(64), 0, stream,
                     mkg(RB, 128, wg3, nullptr, Gh, 64, 128, 0,
                         gat3_as, gat3_ad, sArr, tArr));
  hipLaunchKernelGGL((gat_agg<64, 1>), dim3(aggBlocks), dim3(256), 0, stream,
                     Gh, sArr, tArr, row_start, srcs, gat3_b, Rz, 128);

  // ---- head: lin1 -> fused lin2+lin3 (STE=2, direct store to out) ----
  hipLaunchKernelGGL((gemm_mfma<2, 4, 1, 1, 0>), dim3(GB), dim3(64), 0, stream,
                     mkg(Rz, 128, wl1, lin1_b, RA, 64, 128, 1));
  hipLaunchKernelGGL((gemm_mfma<2, 4, 1, 0, 2>), dim3(GB), dim3(64), 0, stream,
                     mkg(RA, 64, wl2, lin2_b, nullptr, 64, 64, 2,
                         lin3_W, lin3_b, out, nullptr));
}

// Round 7
// 582.953 us; speedup vs baseline: 1.1771x; 1.1124x over previous
//
#include <hip/hip_runtime.h>
#include <math.h>

#define DEV __device__ __forceinline__

typedef __attribute__((ext_vector_type(8))) short short8;   // 8 bf16 (4 VGPRs)
typedef __attribute__((ext_vector_type(4))) float f32x4;    // MFMA acc
typedef float f32x4u __attribute__((ext_vector_type(4), aligned(4)));
typedef __attribute__((ext_vector_type(4))) unsigned int u32x4;
typedef __attribute__((ext_vector_type(4))) _Float16 h16x4;  // 8B of fp16

#define NEG_BIG (-3.0e38f)
#define CAPB 4096   // bucket capacity (mean 2176, +40 sigma)
#define CHUNK 4096  // edges staged per bucket_bin block

DEV float sigm(float x) { return 1.0f / (1.0f + __expf(-x)); }
DEV float leaky(float e) { return (e >= 0.0f) ? e : 0.2f * e; }

// split 8 fp32 -> bf16 hi (truncate) + bf16 lo (truncate of exact residual)
DEV void split_bf16(const float f[8], short8& hi, short8& lo) {
#pragma unroll
  for (int i = 0; i < 8; ++i) {
    unsigned u = __builtin_bit_cast(unsigned, f[i]);
    hi[i] = (short)(u >> 16);
    float h = __builtin_bit_cast(float, u & 0xffff0000u);
    float r = f[i] - h;  // exact (Dekker)
    lo[i] = (short)(__builtin_bit_cast(unsigned, r) >> 16);
  }
}

// fp32 -> packed u32 (bf16hi<<16 | bf16lo); numerics identical to split_bf16
DEV unsigned packsplit(float v) {
  unsigned u = __builtin_bit_cast(unsigned, v);
  unsigned hf = u & 0xffff0000u;
  float r = v - __builtin_bit_cast(float, hf);
  return hf | (__builtin_bit_cast(unsigned, r) >> 16);
}

// unpack 8 packed u32 -> hi/lo short8 via v_perm
DEV void unpack_pk(const u32x4 p0, const u32x4 p1, short8& hi, short8& lo) {
  u32x4 h, l;
  h[0] = __builtin_amdgcn_perm(p0[1], p0[0], 0x07060302u);
  h[1] = __builtin_amdgcn_perm(p0[3], p0[2], 0x07060302u);
  h[2] = __builtin_amdgcn_perm(p1[1], p1[0], 0x07060302u);
  h[3] = __builtin_amdgcn_perm(p1[3], p1[2], 0x07060302u);
  l[0] = __builtin_amdgcn_perm(p0[1], p0[0], 0x05040100u);
  l[1] = __builtin_amdgcn_perm(p0[3], p0[2], 0x05040100u);
  l[2] = __builtin_amdgcn_perm(p1[1], p1[0], 0x05040100u);
  l[3] = __builtin_amdgcn_perm(p1[3], p1[2], 0x05040100u);
  hi = __builtin_bit_cast(short8, h);
  lo = __builtin_bit_cast(short8, l);
}

// MFMA on one 4-tile n-group with compile-time group index G (static acc idx)
template <int G, int MT, int NT>
DEV void mfma_grp(f32x4 (&acc)[MT][NT], const short8 (&ah)[MT],
                  const short8 (&al)[MT], const short8 (&bh)[4],
                  const short8 (&bl)[4]) {
#pragma unroll
  for (int mt = 0; mt < MT; ++mt)
#pragma unroll
    for (int j = 0; j < 4; ++j) {
      acc[mt][G * 4 + j] = __builtin_amdgcn_mfma_f32_16x16x32_bf16(
          ah[mt], bh[j], acc[mt][G * 4 + j], 0, 0, 0);
      acc[mt][G * 4 + j] = __builtin_amdgcn_mfma_f32_16x16x32_bf16(
          ah[mt], bl[j], acc[mt][G * 4 + j], 0, 0, 0);
      acc[mt][G * 4 + j] = __builtin_amdgcn_mfma_f32_16x16x32_bf16(
          al[mt], bh[j], acc[mt][G * 4 + j], 0, 0, 0);
    }
}

// ============================ utility kernels ============================

__global__ void fill_i32_kernel(int* p, int v, int n) {
  int i = blockIdx.x * blockDim.x + threadIdx.x;
  if (i < n) p[i] = v;
}

// ============================ bucketed CSR build ============================

__global__ __launch_bounds__(256) void bucket_bin(
    const int* __restrict__ ei, int* __restrict__ bucket_cnt,
    unsigned* __restrict__ ebuf, int E, int Et) {
  __shared__ unsigned stage[CHUNK];  // 16 KB
  __shared__ int hist[512], rbase[512], lcur[512];
  const int tid = threadIdx.x;
  const long long e0 = (long long)blockIdx.x * CHUNK;
  const int nalive = (int)((Et - e0) < CHUNK ? (Et - e0) : CHUNK);
  for (int i = tid; i < 512; i += 256) hist[i] = 0;
  __syncthreads();
  for (int k = tid; k < nalive; k += 256) {
    long long e = e0 + k;
    int s, d;
    if (e < E) { s = ei[e]; d = ei[E + e]; } else { s = (int)(e - E); d = s; }
    unsigned p = (unsigned)s | ((unsigned)d << 16);  // src:16b | dst:16b
    stage[k] = p;
    atomicAdd(&hist[d >> 7], 1);
  }
  __syncthreads();
  for (int i = tid; i < 512; i += 256) {
    int c = hist[i];
    rbase[i] = c ? atomicAdd(&bucket_cnt[i], c) : 0;
    lcur[i] = 0;
  }
  __syncthreads();
  for (int k = tid; k < nalive; k += 256) {
    unsigned p = stage[k];
    int b = (int)(p >> 23);  // dst>>7
    int lofs = atomicAdd(&lcur[b], 1);
    int pos = rbase[b] + lofs;
    if (pos < CAPB) ebuf[(long long)b * CAPB + pos] = p;
  }
}

__global__ __launch_bounds__(512) void bucket_scan(
    const int* __restrict__ cnt, int* __restrict__ start, int Et) {
  __shared__ int sh[512];
  int tid = threadIdx.x;
  int v = cnt[tid];
  sh[tid] = v;
  __syncthreads();
  int val = v;
  for (int off = 1; off < 512; off <<= 1) {
    int add = (tid >= off) ? sh[tid - off] : 0;
    __syncthreads();
    val += add;
    sh[tid] = val;
    __syncthreads();
  }
  start[tid] = val - v;
  if (tid == 511) start[512] = Et;
}

__global__ __launch_bounds__(128) void bucket_csr(
    const unsigned* __restrict__ ebuf, const int* __restrict__ bucket_cnt,
    const int* __restrict__ bucket_start, int* __restrict__ row_start,
    int* __restrict__ srcs, int N, int Et) {
  __shared__ unsigned stage[CAPB];  // 16 KB
  __shared__ int hist[128], hbase[128], lcur[128];
  const int b = blockIdx.x, tid = threadIdx.x;
  int cnt = bucket_cnt[b];
  cnt = cnt < CAPB ? cnt : CAPB;
  const int gbase = bucket_start[b];
  hist[tid] = 0;
  __syncthreads();
  const unsigned* eb = ebuf + (long long)b * CAPB;
  for (int k = tid; k < cnt; k += 128) {
    unsigned p = eb[k];
    stage[k] = p;
    atomicAdd(&hist[(p >> 16) & 127], 1);
  }
  __syncthreads();
  int v = hist[tid];
  hbase[tid] = v;
  __syncthreads();
  int val = v;
  for (int off = 1; off < 128; off <<= 1) {
    int add = (tid >= off) ? hbase[tid - off] : 0;
    __syncthreads();
    val += add;
    hbase[tid] = val;
    __syncthreads();
  }
  int ex = val - v;
  row_start[b * 128 + tid] = gbase + ex;
  __syncthreads();
  hbase[tid] = ex;
  lcur[tid] = 0;
  __syncthreads();
  for (int k = tid; k < cnt; k += 128) {
    unsigned p = stage[k];
    int o = (p >> 16) & 127;
    int lofs = atomicAdd(&lcur[o], 1);
    srcs[gbase + hbase[o] + lofs] = (int)(p & 0xffffu);
  }
  if (b == 0 && tid == 0) row_start[N] = Et;
}

// ============================ fused W pre-split ============================
struct WJobs {
  const float* W[16];
  short* hi[16];
  short* lo[16];
  int K[16];
  int M16[16];
  int ldw[16];
  int skip[16];
  int tile0[16];
};

__global__ __launch_bounds__(64) void wsplit_all(WJobs jb, int njobs) {
  int b = blockIdx.x;
  int ji = 0;
#pragma unroll
  for (int i = 1; i < 16; ++i)
    if (i < njobs && b >= jb.tile0[i]) ji = i;
  int t = b - jb.tile0[ji];
  int M16 = jb.M16[ji];
  int kc = t / M16, ntG = t % M16;
  int K = jb.K[ji], ldw = jb.ldw[ji];
  const float* __restrict__ W = jb.W[ji];

  int lane = threadIdx.x;
  int kb = kc * 32 + (lane >> 4) * 8;
  int c = ntG * 16 + (lane & 15);
  if (jb.skip[ji] && c >= 64) c += 64;  // skip dead f-gate columns
  float f[8];
#pragma unroll
  for (int j = 0; j < 8; ++j) {
    int k = kb + j;
    f[j] = (k < K) ? W[(long long)k * ldw + c] : 0.0f;
  }
  short8 h, l;
  split_bf16(f, h, l);
  long long off = ((long long)t * 64 + lane) * 8;
  *(short8*)(jb.hi[ji] + off) = h;
  *(short8*)(jb.lo[ji] + off) = l;
}

// ============================ GEMM core loop ============================
// Round 7: loop factored out so layer pairs/chains can be fused through LDS
// (numerics-identical: packsplit -> LDS -> unpack_pk, same as the HBM path).
// APK: 0 = fp32 A (global), 1 = packed-u32 A (global OR LDS pointer).
// abase = row offset into A (global r0, or 0 for LDS-local rows).

template <int MT, int NT, int APK>
DEV void gemm_loop(const void* __restrict__ Av, long long abase, int lda,
                   const short* __restrict__ wh, const short* __restrict__ wl,
                   int K, int KC, f32x4 (&acc)[MT][NT]) {
  const int lane = threadIdx.x;
  const int m = lane & 15, q = lane >> 4;
#pragma unroll
  for (int i = 0; i < MT; ++i)
#pragma unroll
    for (int j = 0; j < NT; ++j) acc[i][j] = (f32x4)(0.0f);

  u32x4 pA[MT][2];
  float fA[MT][8];

  auto loadA = [&](int kc) {
#pragma unroll
    for (int mt = 0; mt < MT; ++mt) {
      if (APK == 1) {
        const unsigned* ap =
            (const unsigned*)Av + (abase + mt * 16 + m) * lda + kc * 32 + q * 8;
        pA[mt][0] = *(const u32x4*)ap;
        pA[mt][1] = *(const u32x4*)(ap + 4);
      } else {
        const float* ap =
            (const float*)Av + (abase + mt * 16 + m) * lda + kc * 32 + q * 8;
        if (kc * 32 + 32 <= K) {
          f32x4u p0 = *(const f32x4u*)ap;
          f32x4u p1 = *(const f32x4u*)(ap + 4);
#pragma unroll
          for (int j = 0; j < 4; ++j) { fA[mt][j] = p0[j]; fA[mt][4 + j] = p1[j]; }
        } else {
#pragma unroll
          for (int j = 0; j < 8; ++j) {
            int k = kc * 32 + q * 8 + j;
            fA[mt][j] = (k < K) ? ap[j] : 0.0f;
          }
        }
      }
    }
  };

  short8 ah[MT], al[MT];
  auto unpackA = [&]() {
#pragma unroll
    for (int mt = 0; mt < MT; ++mt) {
      if (APK == 1)
        unpack_pk(pA[mt][0], pA[mt][1], ah[mt], al[mt]);
      else
        split_bf16(fA[mt], ah[mt], al[mt]);
    }
  };

  short8 bh0[4], bl0[4], bh1[4], bl1[4];
  auto loadB = [&](short8 (&bh)[4], short8 (&bl)[4], int kc, int gg) {
#pragma unroll
    for (int j = 0; j < 4; ++j) {
      long long off = (((long long)kc * NT + (gg * 4 + j)) * 64 + lane) * 8;
      bh[j] = *(const short8*)(wh + off);
      bl[j] = *(const short8*)(wl + off);
    }
  };

  if constexpr (NT == 4) {
    loadA(0);
    loadB(bh0, bl0, 0, 0);
    int kc = 0;
    for (; kc + 2 <= KC; kc += 2) {
      unpackA();
      loadB(bh1, bl1, kc + 1, 0);
      loadA(kc + 1);
      mfma_grp<0, MT, NT>(acc, ah, al, bh0, bl0);
      unpackA();
      if (kc + 2 < KC) {
        loadB(bh0, bl0, kc + 2, 0);
        loadA(kc + 2);
      }
      mfma_grp<0, MT, NT>(acc, ah, al, bh1, bl1);
    }
    if (kc < KC) {
      unpackA();
      mfma_grp<0, MT, NT>(acc, ah, al, bh0, bl0);
    }
  } else {  // NT == 8
    loadA(0);
    loadB(bh0, bl0, 0, 0);
    for (int kc = 0; kc < KC; ++kc) {
      unpackA();
      loadB(bh1, bl1, kc, 1);
      if (kc + 1 < KC) loadA(kc + 1);
      mfma_grp<0, MT, NT>(acc, ah, al, bh0, bl0);
      if (kc + 1 < KC) loadB(bh0, bl0, kc + 1, 0);
      mfma_grp<1, MT, NT>(acc, ah, al, bh1, bl1);
    }
  }
}

// ============================ epilogues ============================

template <int MT, int NT>
DEV void epi_packed(const f32x4 (&acc)[MT][NT], const float* bias,
                    unsigned* C, int ldc, long long r0, int act) {
  const int lane = threadIdx.x;
  const int m = lane & 15, q = lane >> 4;
#pragma unroll
  for (int nt = 0; nt < NT; ++nt) {
    int col = nt * 16 + m;
    float b = bias ? bias[col] : 0.0f;
#pragma unroll
    for (int mt = 0; mt < MT; ++mt) {
      long long rb = r0 + mt * 16 + q * 4;
#pragma unroll
      for (int reg = 0; reg < 4; ++reg) {
        float v = acc[mt][nt][reg] + b;
        if (act) v = fmaxf(v, 0.0f);
        C[(rb + reg) * ldc + col] = packsplit(v);
      }
    }
  }
}

// relu(acc+b) -> packed u32 -> LDS (row stride S u32; S%4==0 for b128 align)
template <int MT, int NT>
DEV void epi_lds(const f32x4 (&acc)[MT][NT], const float* bias,
                 unsigned* L, int S) {
  const int lane = threadIdx.x;
  const int m = lane & 15, q = lane >> 4;
#pragma unroll
  for (int nt = 0; nt < NT; ++nt) {
    int col = nt * 16 + m;
    float b = bias[col];
#pragma unroll
    for (int mt = 0; mt < MT; ++mt)
#pragma unroll
      for (int reg = 0; reg < 4; ++reg) {
        float v = fmaxf(acc[mt][nt][reg] + b, 0.0f);
        L[(mt * 16 + q * 4 + reg) * S + col] = packsplit(v);
      }
  }
}

// ============================ standalone GEMM (GAT / generic) ============================
// OPK: 0=fp32 C, 1=packed u32 C, 2=fp16 C. STE=1: fused s/t epilogue (GAT).
struct GemmArgs {
  const void* A; const short* wh; const short* wl; const float* bias;
  void* C; const float* asrc; const float* adst; float* sOut; float* tOut;
  int lda, ldc, K, KC, act;
};

template <int MT, int NT, int APK, int OPK, int STE>
__global__ __launch_bounds__(64) void gemm_mfma(GemmArgs g) {
  const int lane = threadIdx.x;
  const int m = lane & 15, q = lane >> 4;
  const long long r0 = (long long)blockIdx.x * (MT * 16);
  f32x4 acc[MT][NT];
  gemm_loop<MT, NT, APK>(g.A, r0, g.lda, g.wh, g.wl, g.K, g.KC, acc);

#pragma unroll
  for (int nt = 0; nt < NT; ++nt) {
    int col = nt * 16 + m;
    float bsv = g.bias ? g.bias[col] : 0.0f;
#pragma unroll
    for (int mt = 0; mt < MT; ++mt) {
      long long rb = r0 + mt * 16 + q * 4;
#pragma unroll
      for (int reg = 0; reg < 4; ++reg) {
        float v = acc[mt][nt][reg] + bsv;
        if (g.act == 1) v = fmaxf(v, 0.0f);
        if (OPK == 1)
          ((unsigned*)g.C)[(rb + reg) * g.ldc + col] = packsplit(v);
        else if (OPK == 2)
          ((_Float16*)g.C)[(rb + reg) * g.ldc + col] = (_Float16)v;
        else
          ((float*)g.C)[(rb + reg) * g.ldc + col] = v;
      }
    }
  }

  if (STE == 1) {
    float as[NT], ad[NT];
#pragma unroll
    for (int nt = 0; nt < NT; ++nt) {
      int col = nt * 16 + m;
      as[nt] = g.asrc[col];
      ad[nt] = g.adst[col];
    }
#pragma unroll
    for (int mt = 0; mt < MT; ++mt)
#pragma unroll
      for (int reg = 0; reg < 4; ++reg) {
        float ps = 0.0f, pt = 0.0f;
#pragma unroll
        for (int nt = 0; nt < NT; ++nt) {
          ps = fmaf(acc[mt][nt][reg], as[nt], ps);
          pt = fmaf(acc[mt][nt][reg], ad[nt], pt);
        }
#pragma unroll
        for (int off = 1; off < 16; off <<= 1) {
          ps += __shfl_xor(ps, off, 64);
          pt += __shfl_xor(pt, off, 64);
        }
        if (m == 0) {
          long long r = r0 + mt * 16 + q * 4 + reg;
          g.sOut[r] = ps;
          g.tOut[r] = pt;
        }
      }
  }
}

// ============================ fused layer pairs ============================
// One wave, 32 rows: stage1 (A global) -> LDS packed -> stage2 (A from LDS)
// -> packed global out. Saves the intermediate's HBM write+read entirely.

struct PairJob {
  const void* A; int lda, K1;
  const short *w1h, *w1l; const float* b1;
  const short *w2h, *w2l; const float* b2; int K2;
  unsigned* C; int ldc;
};

template <int NT1, int APK1, int NT2>
DEV void pair_body(const PairJob& j, int bid, unsigned* lbuf) {
  constexpr int S = NT1 * 16 + 4;  // padded; S*4 % 16 == 0 (b128-aligned rows)
  const long long r0 = (long long)bid * 32;
  {
    f32x4 acc[2][NT1];
    gemm_loop<2, NT1, APK1>(j.A, r0, j.lda, j.w1h, j.w1l, j.K1,
                            (j.K1 + 31) / 32, acc);
    epi_lds<2, NT1>(acc, j.b1, lbuf, S);
  }
  {
    f32x4 acc[2][NT2];
    gemm_loop<2, NT2, 1>(lbuf, 0, S, j.w2h, j.w2l, j.K2, (j.K2 + 31) / 32, acc);
    epi_packed<2, NT2>(acc, j.b2, j.C, j.ldc, r0, 1);
  }
}

template <int NT1, int APK1, int NT2>
__global__ __launch_bounds__(64) void pair_kernel(PairJob j) {
  __shared__ __align__(16) unsigned lbuf[32 * 132];
  pair_body<NT1, APK1, NT2>(j, blockIdx.x, lbuf);
}

// ============================ fused LSTM+time chain ============================
// 16 rows/wave: ls0 -> ls1 -> ls2 -> time1 -> time2 all through LDS ping-pong.

struct ChainJob {
  const float* x; int lda;
  const short *w0h, *w0l; const float* b0;
  const short *w1h, *w1l; const float* b1;
  const short *w2h, *w2l; const float* b2;
  const short *t1h, *t1l; const float* tb1;
  const short *t2h, *t2l; const float* tb2;
  unsigned* C; int ldc;
};

// lstm core loop: 16 rows x 12 packed gate tiles (i,g,o), B ping-pong
template <int APK>
DEV void lstm_loop(const void* __restrict__ Av, long long abase, int lda,
                   const short* __restrict__ wh, const short* __restrict__ wl,
                   int K, int KC, f32x4 (&acc)[12]) {
  const int lane = threadIdx.x;
  const int m = lane & 15, q = lane >> 4;
#pragma unroll
  for (int j = 0; j < 12; ++j) acc[j] = (f32x4)(0.0f);

  u32x4 pA[2];
  float fA[8];

  auto loadA = [&](int kc) {
    if (APK == 1) {
      const unsigned* ap =
          (const unsigned*)Av + (abase + m) * lda + kc * 32 + q * 8;
      pA[0] = *(const u32x4*)ap;
      pA[1] = *(const u32x4*)(ap + 4);
    } else {
      const float* ap = (const float*)Av + (abase + m) * lda + kc * 32 + q * 8;
      if (kc * 32 + 32 <= K) {
        f32x4u p0 = *(const f32x4u*)ap;
        f32x4u p1 = *(const f32x4u*)(ap + 4);
#pragma unroll
        for (int j = 0; j < 4; ++j) { fA[j] = p0[j]; fA[4 + j] = p1[j]; }
      } else {
#pragma unroll
        for (int j = 0; j < 8; ++j) {
          int k = kc * 32 + q * 8 + j;
          fA[j] = (k < K) ? ap[j] : 0.0f;
        }
      }
    }
  };

  short8 bh0, bl0, bh1, bl1;
  auto loadB = [&](short8& bh, short8& bl, int kc, int nt) {
    long long off = (((long long)kc * 12 + nt) * 64 + lane) * 8;
    bh = *(const short8*)(wh + off);
    bl = *(const short8*)(wl + off);
  };

  loadA(0);
  loadB(bh0, bl0, 0, 0);
  for (int kc = 0; kc < KC; ++kc) {
    short8 ah, al;
    if (APK == 1)
      unpack_pk(pA[0], pA[1], ah, al);
    else
      split_bf16(fA, ah, al);
    loadB(bh1, bl1, kc, 1);
    if (kc + 1 < KC) loadA(kc + 1);
    const int kn = (kc + 1 < KC) ? kc + 1 : kc;
#pragma unroll
    for (int nt = 0; nt < 12; ++nt) {
      short8& cbh = (nt & 1) ? bh1 : bh0;
      short8& cbl = (nt & 1) ? bl1 : bl0;
      acc[nt] = __builtin_amdgcn_mfma_f32_16x16x32_bf16(ah, cbh, acc[nt], 0, 0, 0);
      acc[nt] = __builtin_amdgcn_mfma_f32_16x16x32_bf16(ah, cbl, acc[nt], 0, 0, 0);
      acc[nt] = __builtin_amdgcn_mfma_f32_16x16x32_bf16(al, cbh, acc[nt], 0, 0, 0);
      if (nt + 2 < 12)
        loadB((nt & 1) ? bh1 : bh0, (nt & 1) ? bl1 : bl0, kc, nt + 2);
      else if (nt + 2 == 12)
        loadB(bh0, bl0, kn, 0);
    }
  }
}

DEV void lstm_epi_lds(const f32x4 (&acc)[12], const float* bias,
                      unsigned* L, int S) {
  const int lane = threadIdx.x;
  const int m = lane & 15, q = lane >> 4;
#pragma unroll
  for (int nt = 0; nt < 4; ++nt) {
    int col = nt * 16 + m;
    float bi = bias[col], bg = bias[128 + col], bo = bias[192 + col];
#pragma unroll
    for (int reg = 0; reg < 4; ++reg) {
      float gi = acc[nt][reg] + bi;
      float gg = acc[nt + 4][reg] + bg;
      float go = acc[nt + 8][reg] + bo;
      float cc = sigm(gi) * tanhf(gg);
      L[(q * 4 + reg) * S + col] = packsplit(sigm(go) * tanhf(cc));
    }
  }
}

DEV void chain_body(const ChainJob& c, int bid, unsigned* lbuf) {
  constexpr int S = 68;  // 64 + 4 pad, 16B-aligned rows
  const long long r0 = (long long)bid * 16;
  unsigned* H0 = lbuf;
  unsigned* H1 = lbuf + 16 * S;
  {
    f32x4 acc[12];
    lstm_loop<0>(c.x, r0, c.lda, c.w0h, c.w0l, 24, 1, acc);
    lstm_epi_lds(acc, c.b0, H0, S);
  }
  {
    f32x4 acc[12];
    lstm_loop<1>(H0, 0, S, c.w1h, c.w1l, 64, 2, acc);
    lstm_epi_lds(acc, c.b1, H1, S);
  }
  {
    f32x4 acc[12];
    lstm_loop<1>(H1, 0, S, c.w2h, c.w2l, 64, 2, acc);
    lstm_epi_lds(acc, c.b2, H0, S);
  }
  {
    f32x4 acc[1][4];
    gemm_loop<1, 4, 1>(H0, 0, S, c.t1h, c.t1l, 64, 2, acc);
    epi_lds<1, 4>(acc, c.tb1, H1, S);
  }
  {
    f32x4 acc[1][4];
    gemm_loop<1, 4, 1>(H1, 0, S, c.t2h, c.t2l, 64, 2, acc);
    epi_packed<1, 4>(acc, c.tb2, c.C, c.ldc, r0, 1);
  }
}

// ============================ tower combo ============================
// svi-pair | poi-pair | lstm-time chain: all read x, disjoint outputs.

__global__ __launch_bounds__(64) void tower_combo(PairJob svi, PairJob poi,
                                                  ChainJob ch, int nA, int nAB) {
  __shared__ __align__(16) unsigned lbuf[32 * 132];  // 16.9 KB, max of jobs
  int bid = blockIdx.x;
  if (bid < nA)
    pair_body<8, 0, 8>(svi, bid, lbuf);
  else if (bid < nAB)
    pair_body<4, 0, 4>(poi, bid - nA, lbuf);
  else
    chain_body(ch, bid - nAB, lbuf);
}

// ============================ fused head ============================
// lin1 (Rz packed) -> LDS -> lin2 -> relu -> dot lin3 -> out. 32 rows/wave.

struct HeadJob {
  const void* A; int lda, K1;
  const short *w1h, *w1l; const float* b1;
  const short *w2h, *w2l; const float* b2; int K2;
  const float* w3; const float* b3; float* out;
};

__global__ __launch_bounds__(64) void head_kernel(HeadJob j) {
  __shared__ __align__(16) unsigned lbuf[32 * 68];
  constexpr int S = 68;
  const int lane = threadIdx.x;
  const int m = lane & 15, q = lane >> 4;
  const long long r0 = (long long)blockIdx.x * 32;
  {
    f32x4 acc[2][4];
    gemm_loop<2, 4, 1>(j.A, r0, j.lda, j.w1h, j.w1l, j.K1, (j.K1 + 31) / 32, acc);
    epi_lds<2, 4>(acc, j.b1, lbuf, S);
  }
  {
    f32x4 acc[2][4];
    gemm_loop<2, 4, 1>(lbuf, 0, S, j.w2h, j.w2l, j.K2, (j.K2 + 31) / 32, acc);
    float w3[4], bs[4];
#pragma unroll
    for (int nt = 0; nt < 4; ++nt) {
      int col = nt * 16 + m;
      w3[nt] = j.w3[col];
      bs[nt] = j.b2[col];
    }
#pragma unroll
    for (int mt = 0; mt < 2; ++mt)
#pragma unroll
      for (int reg = 0; reg < 4; ++reg) {
        float ps = 0.0f;
#pragma unroll
        for (int nt = 0; nt < 4; ++nt) {
          float v = fmaxf(acc[mt][nt][reg] + bs[nt], 0.0f);
          ps = fmaf(v, w3[nt], ps);
        }
#pragma unroll
        for (int off = 1; off < 16; off <<= 1) ps += __shfl_xor(ps, off, 64);
        if (m == 0) j.out[r0 + mt * 16 + q * 4 + reg] = ps + j.b3[0];
      }
  }
}

// ============================ GAT aggregate ============================
// G is fp16 (halved random-gather bytes; round-3 verified bytes-bound).

template <int FO, int OPK>
__global__ __launch_bounds__(256) void gat_agg(
    const _Float16* __restrict__ G, const float* __restrict__ s,
    const float* __restrict__ t, const int* __restrict__ row_start,
    const int* __restrict__ srcs, const float* __restrict__ bias,
    void* __restrict__ outv, int ldc) {
  constexpr int CAP = 128;
  constexpr int LPE = FO / 4;
  constexpr int EPW = 64 / LPE;
  __shared__ float ecache[4][CAP];
  __shared__ int icache[4][CAP];
  const int wv = threadIdx.x >> 6;
  const int lane = threadIdx.x & 63;
  const int d = blockIdx.x * 4 + wv;
  const int start = row_start[d], end = row_start[d + 1];
  const float td = t[d];

  float m = NEG_BIG, dsum = 0.0f;
  for (int j = start + lane; j < end; j += 64) {
    int sj = srcs[j];
    float e = leaky(s[sj] + td);
    int idx = j - start;
    if (idx < CAP) { ecache[wv][idx] = e; icache[wv][idx] = sj; }
    float mn = fmaxf(m, e);
    dsum = dsum * __expf(m - mn) + __expf(e - mn);
    m = mn;
  }
#pragma unroll
  for (int off = 32; off; off >>= 1) {
    float mo = __shfl_xor(m, off, 64);
    float dso = __shfl_xor(dsum, off, 64);
    float mn = fmaxf(m, mo);
    dsum = dsum * __expf(m - mn) + dso * __expf(mo - mn);
    m = mn;
  }
  const float inv = 1.0f / dsum;

  const int deg = end - start;
  const int capdeg = deg < CAP ? deg : CAP;
  for (int idx = lane; idx < capdeg; idx += 64)
    ecache[wv][idx] = __expf(ecache[wv][idx] - m) * inv;
  __syncthreads();

  const int grp = lane / LPE, cl = lane % LPE;
  const _Float16* __restrict__ Gc = G + cl * 4;
  float a0 = 0.0f, a1 = 0.0f, a2 = 0.0f, a3 = 0.0f;
  int idx = grp;
  for (; idx + 3 * EPW < capdeg; idx += 4 * EPW) {
    const int i1 = idx + EPW, i2 = idx + 2 * EPW, i3 = idx + 3 * EPW;
    int s0 = icache[wv][idx], s1 = icache[wv][i1];
    int s2 = icache[wv][i2], s3 = icache[wv][i3];
    float l0 = ecache[wv][idx], l1 = ecache[wv][i1];
    float l2 = ecache[wv][i2], l3 = ecache[wv][i3];
    h16x4 g0 = *(const h16x4*)(Gc + (long long)s0 * FO);
    h16x4 g1 = *(const h16x4*)(Gc + (long long)s1 * FO);
    h16x4 g2 = *(const h16x4*)(Gc + (long long)s2 * FO);
    h16x4 g3 = *(const h16x4*)(Gc + (long long)s3 * FO);
    a0 = fmaf(l0, (float)g0[0], a0); a1 = fmaf(l0, (float)g0[1], a1);
    a2 = fmaf(l0, (float)g0[2], a2); a3 = fmaf(l0, (float)g0[3], a3);
    a0 = fmaf(l1, (float)g1[0], a0); a1 = fmaf(l1, (float)g1[1], a1);
    a2 = fmaf(l1, (float)g1[2], a2); a3 = fmaf(l1, (float)g1[3], a3);
    a0 = fmaf(l2, (float)g2[0], a0); a1 = fmaf(l2, (float)g2[1], a1);
    a2 = fmaf(l2, (float)g2[2], a2); a3 = fmaf(l2, (float)g2[3], a3);
    a0 = fmaf(l3, (float)g3[0], a0); a1 = fmaf(l3, (float)g3[1], a1);
    a2 = fmaf(l3, (float)g3[2], a2); a3 = fmaf(l3, (float)g3[3], a3);
  }
  for (; idx + EPW < capdeg; idx += 2 * EPW) {
    const int i1 = idx + EPW;
    int s0 = icache[wv][idx], s1 = icache[wv][i1];
    float l0 = ecache[wv][idx], l1 = ecache[wv][i1];
    h16x4 g0 = *(const h16x4*)(Gc + (long long)s0 * FO);
    h16x4 g1 = *(const h16x4*)(Gc + (long long)s1 * FO);
    a0 = fmaf(l0, (float)g0[0], a0); a1 = fmaf(l0, (float)g0[1], a1);
    a2 = fmaf(l0, (float)g0[2], a2); a3 = fmaf(l0, (float)g0[3], a3);
    a0 = fmaf(l1, (float)g1[0], a0); a1 = fmaf(l1, (float)g1[1], a1);
    a2 = fmaf(l1, (float)g1[2], a2); a3 = fmaf(l1, (float)g1[3], a3);
  }
  for (; idx < capdeg; idx += EPW) {
    int s0 = icache[wv][idx];
    float l0 = ecache[wv][idx];
    h16x4 g0 = *(const h16x4*)(Gc + (long long)s0 * FO);
    a0 = fmaf(l0, (float)g0[0], a0); a1 = fmaf(l0, (float)g0[1], a1);
    a2 = fmaf(l0, (float)g0[2], a2); a3 = fmaf(l0, (float)g0[3], a3);
  }
  for (; idx < deg; idx += EPW) {
    int s0 = srcs[start + idx];
    float l0 = __expf(leaky(s[s0] + td) - m) * inv;
    h16x4 g0 = *(const h16x4*)(Gc + (long long)s0 * FO);
    a0 = fmaf(l0, (float)g0[0], a0); a1 = fmaf(l0, (float)g0[1], a1);
    a2 = fmaf(l0, (float)g0[2], a2); a3 = fmaf(l0, (float)g0[3], a3);
  }
#pragma unroll
  for (int off = 32; off >= LPE; off >>= 1) {
    a0 += __shfl_xor(a0, off, 64);
    a1 += __shfl_xor(a1, off, 64);
    a2 += __shfl_xor(a2, off, 64);
    a3 += __shfl_xor(a3, off, 64);
  }
  if (grp == 0) {
    f32x4u bs = *(const f32x4u*)(bias + cl * 4);
    float v0 = fmaxf(a0 + bs[0], 0.0f);
    float v1 = fmaxf(a1 + bs[1], 0.0f);
    float v2 = fmaxf(a2 + bs[2], 0.0f);
    float v3 = fmaxf(a3 + bs[3], 0.0f);
    if (OPK == 1) {
      u32x4 pv;
      pv[0] = packsplit(v0); pv[1] = packsplit(v1);
      pv[2] = packsplit(v2); pv[3] = packsplit(v3);
      *(u32x4*)((unsigned*)outv + (long long)d * ldc + cl * 4) = pv;
    } else {
      f32x4u v; v[0] = v0; v[1] = v1; v[2] = v2; v[3] = v3;
      *(f32x4u*)((float*)outv + (long long)d * ldc + cl * 4) = v;
    }
  }
}

// ============================ launcher ============================

struct WSplit { const short* hi; const short* lo; };

extern "C" void kernel_launch(void* const* d_in, const int* in_sizes, int n_in,
                              void* d_out, int out_size, void* d_ws, size_t ws_size,
                              hipStream_t stream) {
  const int N = 65536, E = 1048576;
  const int Et = E + N;

  const float* x        = (const float*)d_in[0];
  const int*   ei       = (const int*)d_in[1];
  const float* poi1_W   = (const float*)d_in[2];
  const float* poi1_b   = (const float*)d_in[3];
  const float* poi2_W   = (const float*)d_in[4];
  const float* poi2_b   = (const float*)d_in[5];
  const float* svi1_W   = (const float*)d_in[6];
  const float* svi1_b   = (const float*)d_in[7];
  const float* svi2_W   = (const float*)d_in[8];
  const float* svi2_b   = (const float*)d_in[9];
  const float* all1_W   = (const float*)d_in[10];
  const float* all1_b   = (const float*)d_in[11];
  const float* all2_W   = (const float*)d_in[12];
  const float* all2_b   = (const float*)d_in[13];
  const float* gat1_W   = (const float*)d_in[14];
  const float* gat1_b   = (const float*)d_in[15];
  const float* gat1_as  = (const float*)d_in[16];
  const float* gat1_ad  = (const float*)d_in[17];
  const float* gat2_W   = (const float*)d_in[18];
  const float* gat2_b   = (const float*)d_in[19];
  const float* gat2_as  = (const float*)d_in[20];
  const float* gat2_ad  = (const float*)d_in[21];
  const float* gat3_W   = (const float*)d_in[22];
  const float* gat3_b   = (const float*)d_in[23];
  const float* gat3_as  = (const float*)d_in[24];
  const float* gat3_ad  = (const float*)d_in[25];
  const float* lstm_Wih0= (const float*)d_in[26];
  const float* lstm_Wih = (const float*)d_in[27];
  const float* lstm_b   = (const float*)d_in[29];
  const float* time1_W  = (const float*)d_in[30];
  const float* time1_b  = (const float*)d_in[31];
  const float* time2_W  = (const float*)d_in[32];
  const float* time2_b  = (const float*)d_in[33];
  const float* lin1_W   = (const float*)d_in[34];
  const float* lin1_b   = (const float*)d_in[35];
  const float* lin2_W   = (const float*)d_in[36];
  const float* lin2_b   = (const float*)d_in[37];
  const float* lin3_W   = (const float*)d_in[38];
  const float* lin3_b   = (const float*)d_in[39];
  float* out = (float*)d_out;

  // ---- workspace layout ----
  float* wsf   = (float*)d_ws;
  float* R192  = wsf;                      // N x 192 packed (tower concat)
  float* RA    = R192 + (size_t)N * 192;   // N x 128 region (fp16 G)
  float* RB    = RA + (size_t)N * 128;     // N x 128 packed
  float* Rz    = RB + (size_t)N * 128;     // N x 128 packed (GAT3 | time2)
  float* sArr  = Rz + (size_t)N * 128;
  float* tArr  = sArr + N;
  int* ints         = (int*)(tArr + N);
  int* row_start    = ints;                        // N+1
  int* srcs         = row_start + (N + 1);         // Et
  int* bucket_cnt   = srcs + Et;                   // 512
  int* bucket_start = bucket_cnt + 512;            // 513
  unsigned* ebuf    = (unsigned*)(bucket_start + 513);  // 512*CAPB (8MB)
  short* pool = (short*)(((uintptr_t)(ebuf + 512 * CAPB) + 15) & ~(uintptr_t)15);

  WJobs jb{};
  int nj = 0, tiles = 0;
  auto split = [&](const float* W, int K, int M, int ldw, int skip) -> WSplit {
    int KC = (K + 31) / 32;
    size_t sz = (size_t)KC * M * 32;
    short* hi = pool; pool += sz;
    short* lo = pool; pool += sz;
    jb.W[nj] = W; jb.hi[nj] = hi; jb.lo[nj] = lo;
    jb.K[nj] = K; jb.M16[nj] = M / 16; jb.ldw[nj] = ldw; jb.skip[nj] = skip;
    jb.tile0[nj] = tiles;
    tiles += KC * (M / 16);
    ++nj;
    return {hi, lo};
  };

  auto mkg = [&](const void* A, int lda, WSplit w, const float* bias, void* C,
                 int ldc, int K, int act, const float* as_ = nullptr,
                 const float* ad_ = nullptr, float* sO = nullptr,
                 float* tO = nullptr) -> GemmArgs {
    GemmArgs g;
    g.A = A; g.lda = lda; g.wh = w.hi; g.wl = w.lo; g.bias = bias;
    g.C = C; g.ldc = ldc; g.K = K; g.KC = (K + 31) / 32; g.act = act;
    g.asrc = as_; g.adst = ad_; g.sOut = sO; g.tOut = tO;
    return g;
  };

  // ---- register all weight splits, then ONE fused split launch ----
  WSplit wpoi1 = split(poi1_W, 13, 64, 64, 0);
  WSplit wpoi2 = split(poi2_W, 64, 64, 64, 0);
  WSplit wsvi1 = split(svi1_W, 365, 128, 128, 0);
  WSplit wsvi2 = split(svi2_W, 128, 128, 128, 0);
  WSplit wall1 = split(all1_W, 192, 128, 128, 0);
  WSplit wall2 = split(all2_W, 128, 128, 128, 0);
  WSplit wg1   = split(gat1_W, 128, 128, 128, 0);
  WSplit wg2   = split(gat2_W, 128, 128, 128, 0);
  WSplit wg3   = split(gat3_W, 128, 64, 64, 0);
  WSplit wls0  = split(lstm_Wih0, 24, 192, 256, 1);
  WSplit wls1  = split(lstm_Wih, 64, 192, 256, 1);
  WSplit wls2  = split(lstm_Wih + 64 * 256, 64, 192, 256, 1);
  WSplit wt1   = split(time1_W, 64, 64, 64, 0);
  WSplit wt2   = split(time2_W, 64, 64, 64, 0);
  WSplit wl1   = split(lin1_W, 128, 64, 64, 0);
  WSplit wl2   = split(lin2_W, 64, 64, 64, 0);
  hipLaunchKernelGGL(wsplit_all, dim3(tiles), dim3(64), 0, stream, jb, nj);

  const int TB = 256;
  const int GB = N / 32;   // 32-row blocks
  const int CB = N / 16;   // 16-row chain blocks

  // ---- build CSR via bucketed counting sort ----
  hipLaunchKernelGGL(fill_i32_kernel, dim3(2), dim3(TB), 0, stream,
                     bucket_cnt, 0, 512);
  hipLaunchKernelGGL(bucket_bin, dim3((Et + CHUNK - 1) / CHUNK), dim3(256),
                     0, stream, ei, bucket_cnt, ebuf, E, Et);
  hipLaunchKernelGGL(bucket_scan, dim3(1), dim3(512), 0, stream,
                     bucket_cnt, bucket_start, Et);
  hipLaunchKernelGGL(bucket_csr, dim3(512), dim3(128), 0, stream,
                     ebuf, bucket_cnt, bucket_start, row_start, srcs, N, Et);

  _Float16* Gh = (_Float16*)RA;  // fp16 G buffer aliases RA region

  // ---- T1: svi-pair | poi-pair | lstm+time chain (all read x) ----
  PairJob svi;
  svi.A = x + 56; svi.lda = 445; svi.K1 = 365;
  svi.w1h = wsvi1.hi; svi.w1l = wsvi1.lo; svi.b1 = svi1_b;
  svi.w2h = wsvi2.hi; svi.w2l = wsvi2.lo; svi.b2 = svi2_b; svi.K2 = 128;
  svi.C = (unsigned*)R192 + 64; svi.ldc = 192;
  PairJob poi;
  poi.A = x + 3; poi.lda = 445; poi.K1 = 13;
  poi.w1h = wpoi1.hi; poi.w1l = wpoi1.lo; poi.b1 = poi1_b;
  poi.w2h = wpoi2.hi; poi.w2l = wpoi2.lo; poi.b2 = poi2_b; poi.K2 = 64;
  poi.C = (unsigned*)R192; poi.ldc = 192;
  ChainJob ch;
  ch.x = x + 421; ch.lda = 445;
  ch.w0h = wls0.hi; ch.w0l = wls0.lo; ch.b0 = lstm_b;
  ch.w1h = wls1.hi; ch.w1l = wls1.lo; ch.b1 = lstm_b + 256;
  ch.w2h = wls2.hi; ch.w2l = wls2.lo; ch.b2 = lstm_b + 512;
  ch.t1h = wt1.hi; ch.t1l = wt1.lo; ch.tb1 = time1_b;
  ch.t2h = wt2.hi; ch.t2l = wt2.lo; ch.tb2 = time2_b;
  ch.C = (unsigned*)Rz + 64; ch.ldc = 128;
  hipLaunchKernelGGL(tower_combo, dim3(GB + GB + CB), dim3(64), 0, stream,
                     svi, poi, ch, GB, GB + GB);

  // ---- T2: all1 -> all2 fused pair (R192 -> RB) ----
  PairJob allp;
  allp.A = R192; allp.lda = 192; allp.K1 = 192;
  allp.w1h = wall1.hi; allp.w1l = wall1.lo; allp.b1 = all1_b;
  allp.w2h = wall2.hi; allp.w2l = wall2.lo; allp.b2 = all2_b; allp.K2 = 128;
  allp.C = (unsigned*)RB; allp.ldc = 128;
  hipLaunchKernelGGL((pair_kernel<8, 1, 8>), dim3(GB), dim3(64), 0, stream,
                     allp);

  const int aggBlocks = N / 4;

  // ---- GAT1 ----
  hipLaunchKernelGGL((gemm_mfma<2, 8, 1, 2, 1>), dim3(GB), dim3(64), 0, stream,
                     mkg(RB, 128, wg1, nullptr, Gh, 128, 128, 0,
                         gat1_as, gat1_ad, sArr, tArr));
  hipLaunchKernelGGL((gat_agg<128, 1>), dim3(aggBlocks), dim3(256), 0, stream,
                     Gh, sArr, tArr, row_start, srcs, gat1_b, RB, 128);
  // ---- GAT2 ----
  hipLaunchKernelGGL((gemm_mfma<2, 8, 1, 2, 1>), dim3(GB), dim3(64), 0, stream,
                     mkg(RB, 128, wg2, nullptr, Gh, 128, 128, 0,
                         gat2_as, gat2_ad, sArr, tArr));
  hipLaunchKernelGGL((gat_agg<128, 1>), dim3(aggBlocks), dim3(256), 0, stream,
                     Gh, sArr, tArr, row_start, srcs, gat2_b, RB, 128);
  // ---- GAT3 (fo=64 -> Rz cols 0..63 packed) ----
  hipLaunchKernelGGL((gemm_mfma<2, 4, 1, 2, 1>), dim3(GB), dim3(64), 0, stream,
                     mkg(RB, 128, wg3, nullptr, Gh, 64, 128, 0,
                         gat3_as, gat3_ad, sArr, tArr));
  hipLaunchKernelGGL((gat_agg<64, 1>), dim3(aggBlocks), dim3(256), 0, stream,
                     Gh, sArr, tArr, row_start, srcs, gat3_b, Rz, 128);

  // ---- head: lin1 -> lin2 -> lin3 fused triple ----
  HeadJob hd;
  hd.A = Rz; hd.lda = 128; hd.K1 = 128;
  hd.w1h = wl1.hi; hd.w1l = wl1.lo; hd.b1 = lin1_b;
  hd.w2h = wl2.hi; hd.w2l = wl2.lo; hd.b2 = lin2_b; hd.K2 = 64;
  hd.w3 = lin3_W; hd.b3 = lin3_b; hd.out = out;
  hipLaunchKernelGGL(head_kernel, dim3(GB), dim3(64), 0, stream, hd);
}